// Round 15
// baseline (592.776 us; speedup 1.0000x reference)
//
#include <hip/hip_runtime.h>
#include <math.h>

#define NN 4096
#define DIM 784
#define K62 62
#define CAP 160
#define NEED 80u

typedef __attribute__((ext_vector_type(8))) short bf16x8;
typedef __attribute__((ext_vector_type(4))) float f32x4;

__device__ __forceinline__ unsigned short f2bf(float f) {
    unsigned u = __float_as_uint(f);
    return (unsigned short)((u + 0x7FFFu + ((u >> 16) & 1u)) >> 16);   // RNE
}

// ---------------- prep (R24): fused sqnorm + bf16 conversion — one pass over x ----------------
__global__ __launch_bounds__(256) void k_prep(const float* __restrict__ x, double* __restrict__ sqnd,
                                              float* __restrict__ sqnf, unsigned short* __restrict__ xb) {
    int r = blockIdx.x * 4 + (threadIdx.x >> 6);
    int lane = threadIdx.x & 63;
    const float* xr = x + (size_t)r * DIM;
    unsigned short* xbr = xb + (size_t)r * 800;
    double s = 0.0;
    for (int k = lane; k < 800; k += 64) {
        if (k < DIM) {
            float v = xr[k];
            s = fma((double)v, (double)v, s);
            xbr[k] = f2bf(v);
        } else {
            xbr[k] = 0;
        }
    }
    for (int o = 32; o > 0; o >>= 1) s += __shfl_down(s, o);
    if (lane == 0) { sqnd[r] = s; sqnf[r] = (float)s; }
}

#define F4C(v, i) ((i) == 0 ? (v).x : (i) == 1 ? (v).y : (i) == 2 ? (v).z : (v).w)

// ---------------- MFMA gram (R23-proven): bf16 16x16x32, direct-global fragments, 16-bit keys ----------------
__global__ __launch_bounds__(256, 2) void k_gram_mfma(const unsigned short* __restrict__ xb,
                                                      const float* __restrict__ sqnf,
                                                      unsigned short* __restrict__ Dm16) {
    __shared__ unsigned short Cs16[64 * 72];
    int t = threadIdx.x;
    int id = blockIdx.x;
    int bi = (int)((sqrtf(8.f * (float)id + 1.f) - 1.f) * 0.5f);
    while ((bi + 1) * (bi + 2) / 2 <= id) ++bi;
    while (bi * (bi + 1) / 2 > id) --bi;
    int bj = id - bi * (bi + 1) / 2;
    int i0 = bi * 128, j0 = bj * 128;
    int wv = t >> 6, ln = t & 63;
    int l16 = ln & 15, kg = ln >> 4;

    f32x4 acc[2][8];
    #pragma unroll
    for (int rt = 0; rt < 2; ++rt)
    #pragma unroll
    for (int ct = 0; ct < 8; ++ct)
    #pragma unroll
    for (int e = 0; e < 4; ++e) acc[rt][ct][e] = 0.f;

    const unsigned short* arow0 = xb + (size_t)(i0 + wv * 32 + l16) * 800 + kg * 8;
    const unsigned short* arow1 = arow0 + 16 * 800;
    const unsigned short* brow  = xb + (size_t)(j0 + l16) * 800 + kg * 8;

    for (int ks = 0; ks < 25; ++ks) {
        bf16x8 a0 = *(const bf16x8*)(arow0 + ks * 32);
        bf16x8 a1 = *(const bf16x8*)(arow1 + ks * 32);
        #pragma unroll
        for (int ct = 0; ct < 8; ++ct) {
            bf16x8 b = *(const bf16x8*)(brow + (size_t)ct * 16 * 800 + ks * 32);
            acc[0][ct] = __builtin_amdgcn_mfma_f32_16x16x32_bf16(a0, b, acc[0][ct], 0, 0, 0);
            acc[1][ct] = __builtin_amdgcn_mfma_f32_16x16x32_bf16(a1, b, acc[1][ct], 0, 0, 0);
        }
    }
    // epilogue: d^2 keys. D[row=(kg*4+j)][col=l16] per 16x16 tile (m89 layout).
    #pragma unroll
    for (int rt = 0; rt < 2; ++rt) {
        int gr0 = i0 + wv * 32 + rt * 16 + kg * 4;
        #pragma unroll
        for (int ct = 0; ct < 8; ++ct) {
            int gc = j0 + ct * 16 + l16;
            float sj = sqnf[gc];
            #pragma unroll
            for (int j = 0; j < 4; ++j) {
                float d2 = fmaxf(sqnf[gr0 + j] + sj - 2.f * acc[rt][ct][j], 1e-12f);
                Dm16[(size_t)(gr0 + j) * NN + gc] = (unsigned short)(__float_as_uint(d2) >> 16);
            }
        }
    }
    // mirror: read tile back (L2-hot), transpose via Cs16, write coalesced.
    if (bi != bj) {
        for (int qr = 0; qr < 2; ++qr)
        for (int qc = 0; qc < 2; ++qc) {
            __syncthreads();
            #pragma unroll
            for (int g = 0; g < 2; ++g) {
                int idx = t + g * 256;
                int a = idx >> 3, c8 = idx & 7;
                uint4 v = *(const uint4*)&Dm16[(size_t)(i0 + qr * 64 + a) * NN + j0 + qc * 64 + c8 * 8];
                Cs16[(c8 * 8 + 0) * 72 + a] = (unsigned short)(v.x);
                Cs16[(c8 * 8 + 1) * 72 + a] = (unsigned short)(v.x >> 16);
                Cs16[(c8 * 8 + 2) * 72 + a] = (unsigned short)(v.y);
                Cs16[(c8 * 8 + 3) * 72 + a] = (unsigned short)(v.y >> 16);
                Cs16[(c8 * 8 + 4) * 72 + a] = (unsigned short)(v.z);
                Cs16[(c8 * 8 + 5) * 72 + a] = (unsigned short)(v.z >> 16);
                Cs16[(c8 * 8 + 6) * 72 + a] = (unsigned short)(v.w);
                Cs16[(c8 * 8 + 7) * 72 + a] = (unsigned short)(v.w >> 16);
            }
            __syncthreads();
            #pragma unroll
            for (int g = 0; g < 2; ++g) {
                int idx = t + g * 256;
                int a = idx >> 3, c8 = idx & 7;
                uint4 v = *(const uint4*)&Cs16[a * 72 + c8 * 8];
                *(uint4*)&Dm16[(size_t)(j0 + qc * 64 + a) * NN + i0 + qr * 64 + c8 * 8] = v;
            }
        }
    }
}

// ---------------- encoder (R25 = R24 with launch_bounds relaxed (512,8)->(512,4)) ----------------
// Two failed container runs on the (512,8) build; only compile-corner novelty was the forced
// 64-VGPR cap (body measured exactly 64 at a 128 cap). (512,4) = cap 128, same target occupancy
// (thread-capped at 4 blocks/CU = 32 waves/CU), allocator headroom. Everything else identical.
// Pre-commit: third failure => abandon 512-thread encoder, revert to green R23 config.
__global__ __launch_bounds__(512, 4) void k_encoder(const float* __restrict__ x,
    const float* __restrict__ cw1, const float* __restrict__ cb1,
    const float* __restrict__ cw2, const float* __restrict__ cb2,
    const float* __restrict__ cw3, const float* __restrict__ cb3,
    const float* __restrict__ dw, const float* __restrict__ db,
    double* __restrict__ Enc, double* __restrict__ esqd)
{
    __shared__ __align__(16) unsigned char SB[23584];
    float*  sb1  = (float*)(SB);             // 32 f
    float*  sb2  = (float*)(SB + 128);       // 32 f
    float*  sb3  = (float*)(SB + 256);       // 16 f
    float*  sdb  = (float*)(SB + 320);       // 16 f
    float*  scw1 = (float*)(SB + 384);       // 288 f  [384,1536)
    float*  wq   = (float*)(SB + 1536);      // 1152 f [1536,6144)  shared conv2/conv3 weights
    float*  wq3  = (float*)(SB + 1536);      // overlay

    int t = threadIdx.x;
    int h = t >> 8, tl = t & 255;            // image half, local thread
    unsigned char* RB = SB + 6144 + h * 8720;
    float*  simg = (float*)RB;               // 900 f (3600 B)
    float*  h1q  = (float*)(RB + 3600);      // 256 pos x 5 words = 1280 f (5120 B)
    float*  h2s  = (float*)RB;               // 49 x 44 f = 8624 B overlay (simg+h1q dead)
    float*  c3   = (float*)RB;               // 784 f overlay (h2s head, post-conv3)
    double* red  = (double*)(RB + 3200);     // 256 d overlay (h2s mid, post-conv3)
    double* se   = (double*)(RB + 5248);     // 16 d

    int n = blockIdx.x * 2 + h;
    for (int idx = tl; idx < 1280; idx += 256) h1q[idx] = 0.f;
    for (int idx = tl; idx < 900; idx += 256) simg[idx] = 0.f;
    __syncthreads();
    if (tl < 196) {
        int row = tl / 7, c4 = tl % 7;
        float4 v = ((const float4*)(x + (size_t)n * DIM))[tl];
        float* d = &simg[(row + 1) * 30 + 1 + c4 * 4];
        d[0] = v.x; d[1] = v.y; d[2] = v.z; d[3] = v.w;
    }
    for (int idx = t; idx < 288; idx += 512) scw1[idx] = cw1[idx];
    if (t < 32) { sb1[t] = cb1[t]; sb2[t] = cb2[t]; }
    if (t < 16) { sb3[t] = cb3[t]; sdb[t] = db[t]; }
    __syncthreads();

    int p2 = tl >> 2, co8 = (tl & 3) * 8;
    int py2 = p2 / 7, px2 = p2 % 7;
    int cbase = ((2 * py2) * 16 + 2 * px2) * 5;
    int ch1 = tl & 3;
    float acc[4][8];   // [dy*2+dx][q]
    if (tl < 196) {
        #pragma unroll
        for (int pp = 0; pp < 4; ++pp)
        #pragma unroll
        for (int q = 0; q < 8; ++q) acc[pp][q] = sb2[co8 + q];
    }

    for (int oct = 0; oct < 8; ++oct) {
        __syncthreads();   // protect h1q/wq from previous octant's readers
        // ---- conv1 + relu + pool (own image), weights hoisted ----
        {
            int co = (oct << 2) + ch1;
            float wv[9];
            #pragma unroll
            for (int tp = 0; tp < 9; ++tp) wv[tp] = scw1[tp * 32 + co];
            float bias = sb1[co];
            for (int o = tl; o < 784; o += 256) {
                int p = o >> 2;
                int py = p / 14, px = p % 14;
                float m = 0.f;
                #pragma unroll
                for (int dy = 0; dy < 2; ++dy)
                #pragma unroll
                for (int dx = 0; dx < 2; ++dx) {
                    const float* sp = &simg[(2 * py + dy + 1) * 30 + (2 * px + dx + 1)];
                    float a = bias;
                    a = fmaf(sp[-31], wv[0], a);
                    a = fmaf(sp[-30], wv[1], a);
                    a = fmaf(sp[-29], wv[2], a);
                    a = fmaf(sp[ -1], wv[3], a);
                    a = fmaf(sp[  0], wv[4], a);
                    a = fmaf(sp[  1], wv[5], a);
                    a = fmaf(sp[ 29], wv[6], a);
                    a = fmaf(sp[ 30], wv[7], a);
                    a = fmaf(sp[ 31], wv[8], a);
                    if (a < 0.f) a = 0.f;
                    if (a > m) m = a;
                }
                h1q[((py + 1) * 16 + (px + 1)) * 5 + ch1] = m;
            }
        }
        // ---- stage cw2 octant (shared, all 512 threads) ----
        for (int w2 = t; w2 < 1152; w2 += 512) {
            int tap = w2 >> 7, k = w2 & 127;
            wq[w2] = cw2[tap * 1024 + oct * 128 + k];
        }
        __syncthreads();
        // ---- conv2 partial accumulate (own image) ----
        if (tl < 196) {
            #pragma unroll
            for (int ky = 0; ky < 3; ++ky)
            #pragma unroll
            for (int kx = 0; kx < 3; ++kx) {
                const float* wb0 = &wq[(ky * 3 + kx) * 128 + co8];
                const float* hb = &h1q[cbase + (ky * 16 + kx) * 5];
                #pragma unroll
                for (int ci = 0; ci < 4; ++ci) {
                    float4 wA = *(const float4*)(wb0 + ci * 32);
                    float4 wB = *(const float4*)(wb0 + ci * 32 + 4);
                    float v00 = hb[ci];
                    float v01 = hb[5 + ci];
                    float v10 = hb[80 + ci];
                    float v11 = hb[85 + ci];
                    acc[0][0] = fmaf(v00, wA.x, acc[0][0]); acc[0][1] = fmaf(v00, wA.y, acc[0][1]);
                    acc[0][2] = fmaf(v00, wA.z, acc[0][2]); acc[0][3] = fmaf(v00, wA.w, acc[0][3]);
                    acc[0][4] = fmaf(v00, wB.x, acc[0][4]); acc[0][5] = fmaf(v00, wB.y, acc[0][5]);
                    acc[0][6] = fmaf(v00, wB.z, acc[0][6]); acc[0][7] = fmaf(v00, wB.w, acc[0][7]);
                    acc[1][0] = fmaf(v01, wA.x, acc[1][0]); acc[1][1] = fmaf(v01, wA.y, acc[1][1]);
                    acc[1][2] = fmaf(v01, wA.z, acc[1][2]); acc[1][3] = fmaf(v01, wA.w, acc[1][3]);
                    acc[1][4] = fmaf(v01, wB.x, acc[1][4]); acc[1][5] = fmaf(v01, wB.y, acc[1][5]);
                    acc[1][6] = fmaf(v01, wB.z, acc[1][6]); acc[1][7] = fmaf(v01, wB.w, acc[1][7]);
                    acc[2][0] = fmaf(v10, wA.x, acc[2][0]); acc[2][1] = fmaf(v10, wA.y, acc[2][1]);
                    acc[2][2] = fmaf(v10, wA.z, acc[2][2]); acc[2][3] = fmaf(v10, wA.w, acc[2][3]);
                    acc[2][4] = fmaf(v10, wB.x, acc[2][4]); acc[2][5] = fmaf(v10, wB.y, acc[2][5]);
                    acc[2][6] = fmaf(v10, wB.z, acc[2][6]); acc[2][7] = fmaf(v10, wB.w, acc[2][7]);
                    acc[3][0] = fmaf(v11, wA.x, acc[3][0]); acc[3][1] = fmaf(v11, wA.y, acc[3][1]);
                    acc[3][2] = fmaf(v11, wA.z, acc[3][2]); acc[3][3] = fmaf(v11, wA.w, acc[3][3]);
                    acc[3][4] = fmaf(v11, wB.x, acc[3][4]); acc[3][5] = fmaf(v11, wB.y, acc[3][5]);
                    acc[3][6] = fmaf(v11, wB.z, acc[3][6]); acc[3][7] = fmaf(v11, wB.w, acc[3][7]);
                }
            }
        }
    }
    __syncthreads();   // last conv2 reads of h1q/wq done; h2s overlay becomes legal
    if (tl < 196) {
        float mm[8];
        #pragma unroll
        for (int q = 0; q < 8; ++q) {
            float m = 0.f;
            #pragma unroll
            for (int pp = 0; pp < 4; ++pp) {
                float a = acc[pp][q];
                if (a < 0.f) a = 0.f;
                if (a > m) m = a;
            }
            mm[q] = m;
        }
        *(float4*)&h2s[p2 * 44 + co8]     = make_float4(mm[0], mm[1], mm[2], mm[3]);
        *(float4*)&h2s[p2 * 44 + co8 + 4] = make_float4(mm[4], mm[5], mm[6], mm[7]);
    }
    float a0 = 0.f, a1 = 0.f, a2 = 0.f, a3 = 0.f;
    int p3 = tl >> 2, co4 = (tl & 3) * 4;
    int py3 = p3 / 7, px3 = p3 % 7;
    if (tl < 196) {
        a0 = sb3[co4]; a1 = sb3[co4 + 1];
        a2 = sb3[co4 + 2]; a3 = sb3[co4 + 3];
    }
    for (int qq = 0; qq < 4; ++qq) {
        __syncthreads();   // h2s written (first iter) / previous quarter's wq3 reads done
        for (int w2 = t; w2 < 1152; w2 += 512) {
            int tap = w2 >> 7, k = w2 & 127;
            wq3[w2] = cw3[tap * 512 + qq * 128 + k];
        }
        __syncthreads();
        if (tl < 196) {
            for (int ky = 0; ky < 3; ++ky) {
                int iy = py3 + ky - 1; if ((unsigned)iy >= 7u) continue;
                for (int kx = 0; kx < 3; ++kx) {
                    int ix = px3 + kx - 1; if ((unsigned)ix >= 7u) continue;
                    const float* hp = &h2s[(iy * 7 + ix) * 44 + qq * 8];
                    float4 h0 = *(const float4*)hp;
                    float4 h1 = *(const float4*)(hp + 4);
                    const float* wp = &wq3[(ky * 3 + kx) * 128 + co4];
                    #pragma unroll
                    for (int ci = 0; ci < 8; ++ci) {
                        float av = (ci < 4) ? F4C(h0, ci) : F4C(h1, ci - 4);
                        float4 wv = *(const float4*)(wp + ci * 16);
                        a0 = fmaf(av, wv.x, a0); a1 = fmaf(av, wv.y, a1);
                        a2 = fmaf(av, wv.z, a2); a3 = fmaf(av, wv.w, a3);
                    }
                }
            }
        }
    }
    __syncthreads();   // all conv3 reads of h2s done -> c3/red overlays legal
    if (tl < 196) {
        float r0 = a0 > 0.f ? a0 : 0.f, r1 = a1 > 0.f ? a1 : 0.f;
        float r2 = a2 > 0.f ? a2 : 0.f, r3 = a3 > 0.f ? a3 : 0.f;
        *(float4*)&c3[p3 * 16 + co4] = make_float4(r0, r1, r2, r3);
    }
    __syncthreads();
    {
        int part = tl >> 4, o = tl & 15, j0 = part * 49;
        double s = 0.0;
        for (int j = 0; j < 49; ++j) s = fma((double)c3[j0 + j], (double)dw[(size_t)(j0 + j) * 16 + o], s);
        red[part * 16 + o] = s;
    }
    __syncthreads();
    if (tl < 16) {
        double e = (double)sdb[tl];
        for (int q = 0; q < 16; ++q) e += red[q * 16 + tl];
        Enc[(size_t)n * 16 + tl] = e;
        se[tl] = e;
    }
    __syncthreads();
    if (tl == 0) {
        double s = 0.0;
        for (int q = 0; q < 16; ++q) s += se[q] * se[q];
        esqd[n] = s;
    }
}

// ---------------- selection (R23-proven): 16-bit key scan, NEED=80, 16-lane-group refine ----------------
__global__ __launch_bounds__(256) void k_topsel(const unsigned short* __restrict__ Dm16,
                                                const double* __restrict__ sqnd,
                                                const float* __restrict__ x,
                                                double* __restrict__ topvd, int* __restrict__ topi) {
    __shared__ float xi[DIM];
    __shared__ unsigned wsum[8];
    __shared__ int cj[CAP];
    __shared__ double cvd[CAP];
    __shared__ unsigned ncnt;
    int i = blockIdx.x, t = threadIdx.x;
    const unsigned* drow = (const unsigned*)(Dm16 + (size_t)i * NN);   // 2048 uints = 4096 keys
    unsigned uk[8];
    #pragma unroll
    for (int s = 0; s < 8; ++s) {
        int wd = t + s * 256;
        unsigned u = drow[wd];
        if (2 * wd == i)     u &= 0xFFFF0000u;   // mask self (low key)
        if (2 * wd + 1 == i) u &= 0x0000FFFFu;   // mask self (high key)
        uk[s] = u;
    }
    if (t < 196) ((float4*)xi)[t] = ((const float4*)(x + (size_t)i * DIM))[t];
    if (t == 0) ncnt = 0;
    int lane = t & 63, w = t >> 6;
    unsigned lo = 0u, hi = 0xFFFFu;
    for (int it = 0; it < 16; ++it) {
        unsigned mid = (lo + hi + 1u) >> 1;
        unsigned cnt = 0;
        #pragma unroll
        for (int s = 0; s < 8; ++s) {
            cnt += ((uk[s] & 0xFFFFu) >= mid) ? 1u : 0u;
            cnt += ((uk[s] >> 16) >= mid) ? 1u : 0u;
        }
        #pragma unroll
        for (int off = 32; off > 0; off >>= 1) cnt += __shfl_down(cnt, off);
        if (lane == 0) wsum[(it & 1) * 4 + w] = cnt;
        __syncthreads();
        int bb = (it & 1) * 4;
        unsigned tot = wsum[bb] + wsum[bb + 1] + wsum[bb + 2] + wsum[bb + 3];
        if (tot >= NEED) lo = mid; else hi = mid - 1u;
    }
    unsigned prefix = lo;   // 16-bit key of the NEED-th-largest distance
    #pragma unroll
    for (int s = 0; s < 8; ++s) {
        int wd = t + s * 256;
        if ((uk[s] & 0xFFFFu) >= prefix) {
            unsigned p = atomicAdd(&ncnt, 1u);
            if (p < CAP) cj[p] = 2 * wd;
        }
        if ((uk[s] >> 16) >= prefix) {
            unsigned p = atomicAdd(&ncnt, 1u);
            if (p < CAP) cj[p] = 2 * wd + 1;
        }
    }
    __syncthreads();
    int ncand = min((int)ncnt, CAP);
    double sqi_d = sqnd[i];
    const float4* xi4 = (const float4*)xi;
    int g = t >> 4, gl = t & 15;   // 16 groups of 16 lanes: 16 gathers in flight
    for (int c = g; c < ncand; c += 16) {
        const float4* xj4 = (const float4*)(x + (size_t)cj[c] * DIM);
        double s = 0.0;
        for (int k = gl; k < 196; k += 16) {
            float4 a = xi4[k]; float4 b = xj4[k];
            s = fma((double)a.x, (double)b.x, s);
            s = fma((double)a.y, (double)b.y, s);
            s = fma((double)a.z, (double)b.z, s);
            s = fma((double)a.w, (double)b.w, s);
        }
        #pragma unroll
        for (int o = 8; o > 0; o >>= 1) s += __shfl_down(s, o, 16);
        if (gl == 0) cvd[c] = sqrt(fmax(sqi_d + sqnd[cj[c]] - 2.0 * s, 1e-12));
    }
    __syncthreads();
    if (t < ncand) {
        double v = cvd[t]; int jj = cj[t];
        int r = 0;
        for (int c2 = 0; c2 < ncand; ++c2) {
            double v2 = cvd[c2];
            if (v2 > v || (v2 == v && cj[c2] < jj)) ++r;
        }
        if (r >= 1 && r < 63) {
            topvd[(size_t)i * K62 + r - 1] = v;
            topi[(size_t)i * K62 + r - 1] = jj;
        }
    }
}

// ---------------- encoded distances + ratio partial ----------------
__global__ __launch_bounds__(256) void k_ratio(const double* __restrict__ Enc, const double* __restrict__ esqd,
                                               const double* __restrict__ topvd, const int* __restrict__ topi,
                                               double* __restrict__ vencd, double* __restrict__ Sp) {
    __shared__ double wp[4];
    int r = blockIdx.x * 4 + (threadIdx.x >> 6);
    int lane = threadIdx.x & 63, w = threadIdx.x >> 6;
    double ratio = 0.0;
    if (lane < K62) {
        int j = topi[(size_t)r * K62 + lane];
        const double* Er = Enc + (size_t)r * 16;
        const double* Ej = Enc + (size_t)j * 16;
        double dot = 0.0;
        #pragma unroll
        for (int q = 0; q < 16; ++q) dot = fma(Er[q], Ej[q], dot);
        double ve = sqrt(fmax(esqd[r] + esqd[j] - 2.0 * dot, 1e-12));
        vencd[(size_t)r * K62 + lane] = ve;
        ratio = topvd[(size_t)r * K62 + lane] / ve;
    }
    for (int o = 32; o > 0; o >>= 1) ratio += __shfl_down(ratio, o);
    if (lane == 0) wp[w] = ratio;
    __syncthreads();
    if (threadIdx.x == 0) Sp[blockIdx.x] = wp[0] + wp[1] + wp[2] + wp[3];
}

// ---------------- loss (merged Sp reduce; identical arithmetic order) ----------------
__global__ __launch_bounds__(256) void k_loss(const double* __restrict__ topvd, const double* __restrict__ vencd,
                                              const double* __restrict__ Sp, double* __restrict__ Lp) {
    __shared__ double wp[4];
    __shared__ double wq2[4];
    int t = threadIdx.x;
    int lane = t & 63, w = t >> 6;
    double sp = Sp[t] + Sp[t + 256] + Sp[t + 512] + Sp[t + 768];
    for (int o = 32; o > 0; o >>= 1) sp += __shfl_down(sp, o);
    if (lane == 0) wp[w] = sp;
    __syncthreads();
    double m = (wp[0] + wp[1] + wp[2] + wp[3]) * (1.0 / (4096.0 * 62.0));
    int r = blockIdx.x * 4 + w;
    double v = -1.0;
    if (lane < K62) {
        double d = topvd[(size_t)r * K62 + lane] - m * vencd[(size_t)r * K62 + lane];
        v = d * d;
    }
    for (int o = 32; o > 0; o >>= 1) { double ov = __shfl_down(v, o); v = (ov > v) ? ov : v; }
    if (lane == 0) wq2[w] = v;
    __syncthreads();
    if (t == 0) Lp[blockIdx.x] = wq2[0] + wq2[1] + wq2[2] + wq2[3];
}

__global__ __launch_bounds__(256) void k_final(const double* __restrict__ Lp, float* __restrict__ out) {
    __shared__ double wp[4];
    int t = threadIdx.x, lane = t & 63, w = t >> 6;
    double s = Lp[t] + Lp[t + 256] + Lp[t + 512] + Lp[t + 768];
    for (int o = 32; o > 0; o >>= 1) s += __shfl_down(s, o);
    if (lane == 0) wp[w] = s;
    __syncthreads();
    if (t == 0) out[0] = (float)((wp[0] + wp[1] + wp[2] + wp[3]) * (1.0 / 4096.0));
}

extern "C" void kernel_launch(void* const* d_in, const int* in_sizes, int n_in,
                              void* d_out, int out_size, void* d_ws, size_t ws_size,
                              hipStream_t stream) {
    const float* x   = (const float*)d_in[0];
    const float* cw1 = (const float*)d_in[1];
    const float* cb1 = (const float*)d_in[2];
    const float* cw2 = (const float*)d_in[3];
    const float* cb2 = (const float*)d_in[4];
    const float* cw3 = (const float*)d_in[5];
    const float* cb3 = (const float*)d_in[6];
    const float* dw  = (const float*)d_in[7];
    const float* db  = (const float*)d_in[8];

    char* wsb = (char*)d_ws;
    unsigned short* Dm16 = (unsigned short*)wsb;           // 4096*4096*2 = 33,554,432 B
    double* Enc   = (double*)(wsb + 33554432);             // 65,536 d
    double* esqd  = (double*)(wsb + 34078720);             // 4,096 d
    double* sqnd  = (double*)(wsb + 34111488);             // 4,096 d
    float*  sqnf  = (float*)(wsb + 34144256);              // 4,096 f
    double* topvd = (double*)(wsb + 34160640);             // 253,952 d
    double* vencd = (double*)(wsb + 36192256);             // 253,952 d
    int*    topi  = (int*)(wsb + 38223872);                // 253,952 i
    double* Sp    = (double*)(wsb + 39239680);             // 1,024 d
    double* Lp    = (double*)(wsb + 39247872);             // 1,024 d
    unsigned short* xb = (unsigned short*)(wsb + 39256064);// 4096*800 bf16 = 6,553,600 B
    float*  out   = (float*)d_out;

    k_prep<<<1024, 256, 0, stream>>>(x, sqnd, sqnf, xb);
    k_gram_mfma<<<528, 256, 0, stream>>>(xb, sqnf, Dm16);
    k_encoder<<<2048, 512, 0, stream>>>(x, cw1, cb1, cw2, cb2, cw3, cb3, dw, db, Enc, esqd);
    k_topsel<<<4096, 256, 0, stream>>>(Dm16, sqnd, x, topvd, topi);
    k_ratio<<<1024, 256, 0, stream>>>(Enc, esqd, topvd, topi, vencd, Sp);
    k_loss<<<1024, 256, 0, stream>>>(topvd, vencd, Sp, Lp);
    k_final<<<1, 256, 0, stream>>>(Lp, out);
}

// Round 16
// 571.189 us; speedup vs baseline: 1.0378x; 1.0378x over previous
//
#include <hip/hip_runtime.h>
#include <math.h>

#define NN 4096
#define DIM 784
#define K62 62
#define CAP 160
#define NEED 80u

typedef __attribute__((ext_vector_type(8))) short bf16x8;
typedef __attribute__((ext_vector_type(4))) float f32x4;

__device__ __forceinline__ unsigned short f2bf(float f) {
    unsigned u = __float_as_uint(f);
    return (unsigned short)((u + 0x7FFFu + ((u >> 16) & 1u)) >> 16);   // RNE
}

// ---------------- prep (R25-proven): fused sqnorm + bf16 conversion — one pass over x ----------------
__global__ __launch_bounds__(256) void k_prep(const float* __restrict__ x, double* __restrict__ sqnd,
                                              float* __restrict__ sqnf, unsigned short* __restrict__ xb) {
    int r = blockIdx.x * 4 + (threadIdx.x >> 6);
    int lane = threadIdx.x & 63;
    const float* xr = x + (size_t)r * DIM;
    unsigned short* xbr = xb + (size_t)r * 800;
    double s = 0.0;
    for (int k = lane; k < 800; k += 64) {
        if (k < DIM) {
            float v = xr[k];
            s = fma((double)v, (double)v, s);
            xbr[k] = f2bf(v);
        } else {
            xbr[k] = 0;
        }
    }
    for (int o = 32; o > 0; o >>= 1) s += __shfl_down(s, o);
    if (lane == 0) { sqnd[r] = s; sqnf[r] = (float)s; }
}

#define F4C(v, i) ((i) == 0 ? (v).x : (i) == 1 ? (v).y : (i) == 2 ? (v).z : (v).w)

// ---------------- MFMA gram (R23-proven): bf16 16x16x32, direct-global fragments, 16-bit keys ----------------
__global__ __launch_bounds__(256, 2) void k_gram_mfma(const unsigned short* __restrict__ xb,
                                                      const float* __restrict__ sqnf,
                                                      unsigned short* __restrict__ Dm16) {
    __shared__ unsigned short Cs16[64 * 72];
    int t = threadIdx.x;
    int id = blockIdx.x;
    int bi = (int)((sqrtf(8.f * (float)id + 1.f) - 1.f) * 0.5f);
    while ((bi + 1) * (bi + 2) / 2 <= id) ++bi;
    while (bi * (bi + 1) / 2 > id) --bi;
    int bj = id - bi * (bi + 1) / 2;
    int i0 = bi * 128, j0 = bj * 128;
    int wv = t >> 6, ln = t & 63;
    int l16 = ln & 15, kg = ln >> 4;

    f32x4 acc[2][8];
    #pragma unroll
    for (int rt = 0; rt < 2; ++rt)
    #pragma unroll
    for (int ct = 0; ct < 8; ++ct)
    #pragma unroll
    for (int e = 0; e < 4; ++e) acc[rt][ct][e] = 0.f;

    const unsigned short* arow0 = xb + (size_t)(i0 + wv * 32 + l16) * 800 + kg * 8;
    const unsigned short* arow1 = arow0 + 16 * 800;
    const unsigned short* brow  = xb + (size_t)(j0 + l16) * 800 + kg * 8;

    for (int ks = 0; ks < 25; ++ks) {
        bf16x8 a0 = *(const bf16x8*)(arow0 + ks * 32);
        bf16x8 a1 = *(const bf16x8*)(arow1 + ks * 32);
        #pragma unroll
        for (int ct = 0; ct < 8; ++ct) {
            bf16x8 b = *(const bf16x8*)(brow + (size_t)ct * 16 * 800 + ks * 32);
            acc[0][ct] = __builtin_amdgcn_mfma_f32_16x16x32_bf16(a0, b, acc[0][ct], 0, 0, 0);
            acc[1][ct] = __builtin_amdgcn_mfma_f32_16x16x32_bf16(a1, b, acc[1][ct], 0, 0, 0);
        }
    }
    // epilogue: d^2 keys. D[row=(kg*4+j)][col=l16] per 16x16 tile (m89 layout).
    #pragma unroll
    for (int rt = 0; rt < 2; ++rt) {
        int gr0 = i0 + wv * 32 + rt * 16 + kg * 4;
        #pragma unroll
        for (int ct = 0; ct < 8; ++ct) {
            int gc = j0 + ct * 16 + l16;
            float sj = sqnf[gc];
            #pragma unroll
            for (int j = 0; j < 4; ++j) {
                float d2 = fmaxf(sqnf[gr0 + j] + sj - 2.f * acc[rt][ct][j], 1e-12f);
                Dm16[(size_t)(gr0 + j) * NN + gc] = (unsigned short)(__float_as_uint(d2) >> 16);
            }
        }
    }
    // mirror: read tile back (L2-hot), transpose via Cs16, write coalesced.
    if (bi != bj) {
        for (int qr = 0; qr < 2; ++qr)
        for (int qc = 0; qc < 2; ++qc) {
            __syncthreads();
            #pragma unroll
            for (int g = 0; g < 2; ++g) {
                int idx = t + g * 256;
                int a = idx >> 3, c8 = idx & 7;
                uint4 v = *(const uint4*)&Dm16[(size_t)(i0 + qr * 64 + a) * NN + j0 + qc * 64 + c8 * 8];
                Cs16[(c8 * 8 + 0) * 72 + a] = (unsigned short)(v.x);
                Cs16[(c8 * 8 + 1) * 72 + a] = (unsigned short)(v.x >> 16);
                Cs16[(c8 * 8 + 2) * 72 + a] = (unsigned short)(v.y);
                Cs16[(c8 * 8 + 3) * 72 + a] = (unsigned short)(v.y >> 16);
                Cs16[(c8 * 8 + 4) * 72 + a] = (unsigned short)(v.z);
                Cs16[(c8 * 8 + 5) * 72 + a] = (unsigned short)(v.z >> 16);
                Cs16[(c8 * 8 + 6) * 72 + a] = (unsigned short)(v.w);
                Cs16[(c8 * 8 + 7) * 72 + a] = (unsigned short)(v.w >> 16);
            }
            __syncthreads();
            #pragma unroll
            for (int g = 0; g < 2; ++g) {
                int idx = t + g * 256;
                int a = idx >> 3, c8 = idx & 7;
                uint4 v = *(const uint4*)&Cs16[a * 72 + c8 * 8];
                *(uint4*)&Dm16[(size_t)(j0 + qc * 64 + a) * NN + i0 + qr * 64 + c8 * 8] = v;
            }
        }
    }
}

// ---------------- encoder (R26 = exact R23/R20 standalone body; 512-thread variant abandoned) ----------------
// R25 post-mortem: the 2-image 512-thread encoder spilled (WRITE_SIZE 5.8 -> 57 MB, the R21
// signature; 350 us > 326). Pre-commit honored: revert to this proven 256-thread body
// (measured 326 us, VGPR 64, WRITE 5.8 MB standalone in R23/R25-adjacent runs).
__global__ __launch_bounds__(256, 4) void k_encoder(const float* __restrict__ x,
    const float* __restrict__ cw1, const float* __restrict__ cb1,
    const float* __restrict__ cw2, const float* __restrict__ cb2,
    const float* __restrict__ cw3, const float* __restrict__ cb3,
    const float* __restrict__ dw, const float* __restrict__ db,
    double* __restrict__ Enc, double* __restrict__ esqd)
{
    __shared__ __align__(16) unsigned char SB[17408];
    float*  sb1  = (float*)(SB);             // 32 f
    float*  sb2  = (float*)(SB + 128);       // 32 f
    float*  sb3  = (float*)(SB + 256);       // 16 f
    float*  sdb  = (float*)(SB + 320);       // 16 f
    float*  scw1 = (float*)(SB + 384);       // 288 f  [384,1536)
    float*  wq   = (float*)(SB + 1536);      // 1152 f [1536,6144)
    float*  simg = (float*)(SB + 6144);      // 900 f  [6144,9744)
    float*  h1q  = (float*)(SB + 9744);      // 256 pos x 5 words = 1280 f [9744,14864)
    float*  wq3  = (float*)(SB + 1536);      // conv3 weights over wq
    float*  h2s  = (float*)(SB + 6144);      // 49 x 44 f = 8624 B [6144,14768) over simg+h1q (dead)
    float*  c3   = (float*)(SB + 6144);      // 784 f over dead h2s head
    double* red  = (double*)(SB + 14768);    // 256 d [14768,16816) over dead h1q tail
    double* se   = (double*)(SB + 16816);    // 16 d [16816,16944)

    int t = threadIdx.x;
    int n = blockIdx.x;
    for (int idx = t; idx < 1280; idx += 256) h1q[idx] = 0.f;
    for (int idx = t; idx < 900; idx += 256) simg[idx] = 0.f;
    __syncthreads();
    if (t < 196) {
        int row = t / 7, c4 = t % 7;
        float4 v = ((const float4*)(x + (size_t)n * DIM))[t];
        float* d = &simg[(row + 1) * 30 + 1 + c4 * 4];
        d[0] = v.x; d[1] = v.y; d[2] = v.z; d[3] = v.w;
    }
    for (int idx = t; idx < 288; idx += 256) scw1[idx] = cw1[idx];
    if (t < 32) { sb1[t] = cb1[t]; sb2[t] = cb2[t]; }
    if (t < 16) { sb3[t] = cb3[t]; sdb[t] = db[t]; }
    __syncthreads();

    int p2 = t >> 2, co8 = (t & 3) * 8;
    int py2 = p2 / 7, px2 = p2 % 7;
    int cbase = ((2 * py2) * 16 + 2 * px2) * 5;
    int ch1 = t & 3;
    float acc[4][8];   // [dy*2+dx][q]
    if (t < 196) {
        #pragma unroll
        for (int pp = 0; pp < 4; ++pp)
        #pragma unroll
        for (int q = 0; q < 8; ++q) acc[pp][q] = sb2[co8 + q];
    }

    for (int oct = 0; oct < 8; ++oct) {
        __syncthreads();   // protect h1q/wq from previous octant's readers
        // ---- conv1 + relu + pool, weights hoisted (loop-invariant per octant) ----
        {
            int co = (oct << 2) + ch1;
            float wv[9];
            #pragma unroll
            for (int tp = 0; tp < 9; ++tp) wv[tp] = scw1[tp * 32 + co];
            float bias = sb1[co];
            for (int o = t; o < 784; o += 256) {
                int p = o >> 2;
                int py = p / 14, px = p % 14;
                float m = 0.f;
                #pragma unroll
                for (int dy = 0; dy < 2; ++dy)
                #pragma unroll
                for (int dx = 0; dx < 2; ++dx) {
                    const float* sp = &simg[(2 * py + dy + 1) * 30 + (2 * px + dx + 1)];
                    float a = bias;
                    a = fmaf(sp[-31], wv[0], a);
                    a = fmaf(sp[-30], wv[1], a);
                    a = fmaf(sp[-29], wv[2], a);
                    a = fmaf(sp[ -1], wv[3], a);
                    a = fmaf(sp[  0], wv[4], a);
                    a = fmaf(sp[  1], wv[5], a);
                    a = fmaf(sp[ 29], wv[6], a);
                    a = fmaf(sp[ 30], wv[7], a);
                    a = fmaf(sp[ 31], wv[8], a);
                    if (a < 0.f) a = 0.f;
                    if (a > m) m = a;
                }
                h1q[((py + 1) * 16 + (px + 1)) * 5 + ch1] = m;
            }
        }
        // ---- stage cw2 octant ----
        for (int w2 = t; w2 < 1152; w2 += 256) {
            int tap = w2 >> 7, k = w2 & 127;
            wq[w2] = cw2[tap * 1024 + oct * 128 + k];
        }
        __syncthreads();
        // ---- conv2 partial accumulate ----
        if (t < 196) {
            #pragma unroll
            for (int ky = 0; ky < 3; ++ky)
            #pragma unroll
            for (int kx = 0; kx < 3; ++kx) {
                const float* wb0 = &wq[(ky * 3 + kx) * 128 + co8];
                const float* hb = &h1q[cbase + (ky * 16 + kx) * 5];
                #pragma unroll
                for (int ci = 0; ci < 4; ++ci) {
                    float4 wA = *(const float4*)(wb0 + ci * 32);
                    float4 wB = *(const float4*)(wb0 + ci * 32 + 4);
                    float v00 = hb[ci];
                    float v01 = hb[5 + ci];
                    float v10 = hb[80 + ci];
                    float v11 = hb[85 + ci];
                    acc[0][0] = fmaf(v00, wA.x, acc[0][0]); acc[0][1] = fmaf(v00, wA.y, acc[0][1]);
                    acc[0][2] = fmaf(v00, wA.z, acc[0][2]); acc[0][3] = fmaf(v00, wA.w, acc[0][3]);
                    acc[0][4] = fmaf(v00, wB.x, acc[0][4]); acc[0][5] = fmaf(v00, wB.y, acc[0][5]);
                    acc[0][6] = fmaf(v00, wB.z, acc[0][6]); acc[0][7] = fmaf(v00, wB.w, acc[0][7]);
                    acc[1][0] = fmaf(v01, wA.x, acc[1][0]); acc[1][1] = fmaf(v01, wA.y, acc[1][1]);
                    acc[1][2] = fmaf(v01, wA.z, acc[1][2]); acc[1][3] = fmaf(v01, wA.w, acc[1][3]);
                    acc[1][4] = fmaf(v01, wB.x, acc[1][4]); acc[1][5] = fmaf(v01, wB.y, acc[1][5]);
                    acc[1][6] = fmaf(v01, wB.z, acc[1][6]); acc[1][7] = fmaf(v01, wB.w, acc[1][7]);
                    acc[2][0] = fmaf(v10, wA.x, acc[2][0]); acc[2][1] = fmaf(v10, wA.y, acc[2][1]);
                    acc[2][2] = fmaf(v10, wA.z, acc[2][2]); acc[2][3] = fmaf(v10, wA.w, acc[2][3]);
                    acc[2][4] = fmaf(v10, wB.x, acc[2][4]); acc[2][5] = fmaf(v10, wB.y, acc[2][5]);
                    acc[2][6] = fmaf(v10, wB.z, acc[2][6]); acc[2][7] = fmaf(v10, wB.w, acc[2][7]);
                    acc[3][0] = fmaf(v11, wA.x, acc[3][0]); acc[3][1] = fmaf(v11, wA.y, acc[3][1]);
                    acc[3][2] = fmaf(v11, wA.z, acc[3][2]); acc[3][3] = fmaf(v11, wA.w, acc[3][3]);
                    acc[3][4] = fmaf(v11, wB.x, acc[3][4]); acc[3][5] = fmaf(v11, wB.y, acc[3][5]);
                    acc[3][6] = fmaf(v11, wB.z, acc[3][6]); acc[3][7] = fmaf(v11, wB.w, acc[3][7]);
                }
            }
        }
    }
    __syncthreads();   // last conv2 reads of h1q/wq done; h2s overlay becomes legal
    if (t < 196) {
        float mm[8];
        #pragma unroll
        for (int q = 0; q < 8; ++q) {
            float m = 0.f;
            #pragma unroll
            for (int pp = 0; pp < 4; ++pp) {
                float a = acc[pp][q];
                if (a < 0.f) a = 0.f;
                if (a > m) m = a;
            }
            mm[q] = m;
        }
        *(float4*)&h2s[p2 * 44 + co8]     = make_float4(mm[0], mm[1], mm[2], mm[3]);
        *(float4*)&h2s[p2 * 44 + co8 + 4] = make_float4(mm[4], mm[5], mm[6], mm[7]);
    }
    float a0 = 0.f, a1 = 0.f, a2 = 0.f, a3 = 0.f;
    int p3 = t >> 2, co4 = (t & 3) * 4;
    int py3 = p3 / 7, px3 = p3 % 7;
    if (t < 196) {
        a0 = sb3[co4]; a1 = sb3[co4 + 1];
        a2 = sb3[co4 + 2]; a3 = sb3[co4 + 3];
    }
    for (int qq = 0; qq < 4; ++qq) {
        __syncthreads();
        for (int w2 = t; w2 < 1152; w2 += 256) {
            int tap = w2 >> 7, k = w2 & 127;
            wq3[w2] = cw3[tap * 512 + qq * 128 + k];
        }
        __syncthreads();
        if (t < 196) {
            for (int ky = 0; ky < 3; ++ky) {
                int iy = py3 + ky - 1; if ((unsigned)iy >= 7u) continue;
                for (int kx = 0; kx < 3; ++kx) {
                    int ix = px3 + kx - 1; if ((unsigned)ix >= 7u) continue;
                    const float* hp = &h2s[(iy * 7 + ix) * 44 + qq * 8];
                    float4 h0 = *(const float4*)hp;
                    float4 h1 = *(const float4*)(hp + 4);
                    const float* wp = &wq3[(ky * 3 + kx) * 128 + co4];
                    #pragma unroll
                    for (int ci = 0; ci < 8; ++ci) {
                        float av = (ci < 4) ? F4C(h0, ci) : F4C(h1, ci - 4);
                        float4 wv = *(const float4*)(wp + ci * 16);
                        a0 = fmaf(av, wv.x, a0); a1 = fmaf(av, wv.y, a1);
                        a2 = fmaf(av, wv.z, a2); a3 = fmaf(av, wv.w, a3);
                    }
                }
            }
        }
    }
    __syncthreads();   // all conv3 reads of h2s done -> c3 may overwrite h2s head
    if (t < 196) {
        float r0 = a0 > 0.f ? a0 : 0.f, r1 = a1 > 0.f ? a1 : 0.f;
        float r2 = a2 > 0.f ? a2 : 0.f, r3 = a3 > 0.f ? a3 : 0.f;
        *(float4*)&c3[p3 * 16 + co4] = make_float4(r0, r1, r2, r3);
    }
    __syncthreads();
    {
        int part = t >> 4, o = t & 15, j0 = part * 49;
        double s = 0.0;
        for (int j = 0; j < 49; ++j) s = fma((double)c3[j0 + j], (double)dw[(size_t)(j0 + j) * 16 + o], s);
        red[part * 16 + o] = s;
    }
    __syncthreads();
    if (t < 16) {
        double e = (double)sdb[t];
        for (int q = 0; q < 16; ++q) e += red[q * 16 + t];
        Enc[(size_t)n * 16 + t] = e;
        se[t] = e;
    }
    __syncthreads();
    if (t == 0) {
        double s = 0.0;
        for (int q = 0; q < 16; ++q) s += se[q] * se[q];
        esqd[n] = s;
    }
}

// ---------------- selection (R23-proven): 16-bit key scan, NEED=80, 16-lane-group refine ----------------
__global__ __launch_bounds__(256) void k_topsel(const unsigned short* __restrict__ Dm16,
                                                const double* __restrict__ sqnd,
                                                const float* __restrict__ x,
                                                double* __restrict__ topvd, int* __restrict__ topi) {
    __shared__ float xi[DIM];
    __shared__ unsigned wsum[8];
    __shared__ int cj[CAP];
    __shared__ double cvd[CAP];
    __shared__ unsigned ncnt;
    int i = blockIdx.x, t = threadIdx.x;
    const unsigned* drow = (const unsigned*)(Dm16 + (size_t)i * NN);   // 2048 uints = 4096 keys
    unsigned uk[8];
    #pragma unroll
    for (int s = 0; s < 8; ++s) {
        int wd = t + s * 256;
        unsigned u = drow[wd];
        if (2 * wd == i)     u &= 0xFFFF0000u;   // mask self (low key)
        if (2 * wd + 1 == i) u &= 0x0000FFFFu;   // mask self (high key)
        uk[s] = u;
    }
    if (t < 196) ((float4*)xi)[t] = ((const float4*)(x + (size_t)i * DIM))[t];
    if (t == 0) ncnt = 0;
    int lane = t & 63, w = t >> 6;
    unsigned lo = 0u, hi = 0xFFFFu;
    for (int it = 0; it < 16; ++it) {
        unsigned mid = (lo + hi + 1u) >> 1;
        unsigned cnt = 0;
        #pragma unroll
        for (int s = 0; s < 8; ++s) {
            cnt += ((uk[s] & 0xFFFFu) >= mid) ? 1u : 0u;
            cnt += ((uk[s] >> 16) >= mid) ? 1u : 0u;
        }
        #pragma unroll
        for (int off = 32; off > 0; off >>= 1) cnt += __shfl_down(cnt, off);
        if (lane == 0) wsum[(it & 1) * 4 + w] = cnt;
        __syncthreads();
        int bb = (it & 1) * 4;
        unsigned tot = wsum[bb] + wsum[bb + 1] + wsum[bb + 2] + wsum[bb + 3];
        if (tot >= NEED) lo = mid; else hi = mid - 1u;
    }
    unsigned prefix = lo;   // 16-bit key of the NEED-th-largest distance
    #pragma unroll
    for (int s = 0; s < 8; ++s) {
        int wd = t + s * 256;
        if ((uk[s] & 0xFFFFu) >= prefix) {
            unsigned p = atomicAdd(&ncnt, 1u);
            if (p < CAP) cj[p] = 2 * wd;
        }
        if ((uk[s] >> 16) >= prefix) {
            unsigned p = atomicAdd(&ncnt, 1u);
            if (p < CAP) cj[p] = 2 * wd + 1;
        }
    }
    __syncthreads();
    int ncand = min((int)ncnt, CAP);
    double sqi_d = sqnd[i];
    const float4* xi4 = (const float4*)xi;
    int g = t >> 4, gl = t & 15;   // 16 groups of 16 lanes: 16 gathers in flight
    for (int c = g; c < ncand; c += 16) {
        const float4* xj4 = (const float4*)(x + (size_t)cj[c] * DIM);
        double s = 0.0;
        for (int k = gl; k < 196; k += 16) {
            float4 a = xi4[k]; float4 b = xj4[k];
            s = fma((double)a.x, (double)b.x, s);
            s = fma((double)a.y, (double)b.y, s);
            s = fma((double)a.z, (double)b.z, s);
            s = fma((double)a.w, (double)b.w, s);
        }
        #pragma unroll
        for (int o = 8; o > 0; o >>= 1) s += __shfl_down(s, o, 16);
        if (gl == 0) cvd[c] = sqrt(fmax(sqi_d + sqnd[cj[c]] - 2.0 * s, 1e-12));
    }
    __syncthreads();
    if (t < ncand) {
        double v = cvd[t]; int jj = cj[t];
        int r = 0;
        for (int c2 = 0; c2 < ncand; ++c2) {
            double v2 = cvd[c2];
            if (v2 > v || (v2 == v && cj[c2] < jj)) ++r;
        }
        if (r >= 1 && r < 63) {
            topvd[(size_t)i * K62 + r - 1] = v;
            topi[(size_t)i * K62 + r - 1] = jj;
        }
    }
}

// ---------------- encoded distances + ratio partial ----------------
__global__ __launch_bounds__(256) void k_ratio(const double* __restrict__ Enc, const double* __restrict__ esqd,
                                               const double* __restrict__ topvd, const int* __restrict__ topi,
                                               double* __restrict__ vencd, double* __restrict__ Sp) {
    __shared__ double wp[4];
    int r = blockIdx.x * 4 + (threadIdx.x >> 6);
    int lane = threadIdx.x & 63, w = threadIdx.x >> 6;
    double ratio = 0.0;
    if (lane < K62) {
        int j = topi[(size_t)r * K62 + lane];
        const double* Er = Enc + (size_t)r * 16;
        const double* Ej = Enc + (size_t)j * 16;
        double dot = 0.0;
        #pragma unroll
        for (int q = 0; q < 16; ++q) dot = fma(Er[q], Ej[q], dot);
        double ve = sqrt(fmax(esqd[r] + esqd[j] - 2.0 * dot, 1e-12));
        vencd[(size_t)r * K62 + lane] = ve;
        ratio = topvd[(size_t)r * K62 + lane] / ve;
    }
    for (int o = 32; o > 0; o >>= 1) ratio += __shfl_down(ratio, o);
    if (lane == 0) wp[w] = ratio;
    __syncthreads();
    if (threadIdx.x == 0) Sp[blockIdx.x] = wp[0] + wp[1] + wp[2] + wp[3];
}

// ---------------- loss (merged Sp reduce; identical arithmetic order) ----------------
__global__ __launch_bounds__(256) void k_loss(const double* __restrict__ topvd, const double* __restrict__ vencd,
                                              const double* __restrict__ Sp, double* __restrict__ Lp) {
    __shared__ double wp[4];
    __shared__ double wq2[4];
    int t = threadIdx.x;
    int lane = t & 63, w = t >> 6;
    double sp = Sp[t] + Sp[t + 256] + Sp[t + 512] + Sp[t + 768];
    for (int o = 32; o > 0; o >>= 1) sp += __shfl_down(sp, o);
    if (lane == 0) wp[w] = sp;
    __syncthreads();
    double m = (wp[0] + wp[1] + wp[2] + wp[3]) * (1.0 / (4096.0 * 62.0));
    int r = blockIdx.x * 4 + w;
    double v = -1.0;
    if (lane < K62) {
        double d = topvd[(size_t)r * K62 + lane] - m * vencd[(size_t)r * K62 + lane];
        v = d * d;
    }
    for (int o = 32; o > 0; o >>= 1) { double ov = __shfl_down(v, o); v = (ov > v) ? ov : v; }
    if (lane == 0) wq2[w] = v;
    __syncthreads();
    if (t == 0) Lp[blockIdx.x] = wq2[0] + wq2[1] + wq2[2] + wq2[3];
}

__global__ __launch_bounds__(256) void k_final(const double* __restrict__ Lp, float* __restrict__ out) {
    __shared__ double wp[4];
    int t = threadIdx.x, lane = t & 63, w = t >> 6;
    double s = Lp[t] + Lp[t + 256] + Lp[t + 512] + Lp[t + 768];
    for (int o = 32; o > 0; o >>= 1) s += __shfl_down(s, o);
    if (lane == 0) wp[w] = s;
    __syncthreads();
    if (t == 0) out[0] = (float)((wp[0] + wp[1] + wp[2] + wp[3]) * (1.0 / 4096.0));
}

extern "C" void kernel_launch(void* const* d_in, const int* in_sizes, int n_in,
                              void* d_out, int out_size, void* d_ws, size_t ws_size,
                              hipStream_t stream) {
    const float* x   = (const float*)d_in[0];
    const float* cw1 = (const float*)d_in[1];
    const float* cb1 = (const float*)d_in[2];
    const float* cw2 = (const float*)d_in[3];
    const float* cb2 = (const float*)d_in[4];
    const float* cw3 = (const float*)d_in[5];
    const float* cb3 = (const float*)d_in[6];
    const float* dw  = (const float*)d_in[7];
    const float* db  = (const float*)d_in[8];

    char* wsb = (char*)d_ws;
    unsigned short* Dm16 = (unsigned short*)wsb;           // 4096*4096*2 = 33,554,432 B
    double* Enc   = (double*)(wsb + 33554432);             // 65,536 d
    double* esqd  = (double*)(wsb + 34078720);             // 4,096 d
    double* sqnd  = (double*)(wsb + 34111488);             // 4,096 d
    float*  sqnf  = (float*)(wsb + 34144256);              // 4,096 f
    double* topvd = (double*)(wsb + 34160640);             // 253,952 d
    double* vencd = (double*)(wsb + 36192256);             // 253,952 d
    int*    topi  = (int*)(wsb + 38223872);                // 253,952 i
    double* Sp    = (double*)(wsb + 39239680);             // 1,024 d
    double* Lp    = (double*)(wsb + 39247872);             // 1,024 d
    unsigned short* xb = (unsigned short*)(wsb + 39256064);// 4096*800 bf16 = 6,553,600 B
    float*  out   = (float*)d_out;

    k_prep<<<1024, 256, 0, stream>>>(x, sqnd, sqnf, xb);
    k_gram_mfma<<<528, 256, 0, stream>>>(xb, sqnf, Dm16);
    k_encoder<<<4096, 256, 0, stream>>>(x, cw1, cb1, cw2, cb2, cw3, cb3, dw, db, Enc, esqd);
    k_topsel<<<4096, 256, 0, stream>>>(Dm16, sqnd, x, topvd, topi);
    k_ratio<<<1024, 256, 0, stream>>>(Enc, esqd, topvd, topi, vencd, Sp);
    k_loss<<<1024, 256, 0, stream>>>(topvd, vencd, Sp, Lp);
    k_final<<<1, 256, 0, stream>>>(Lp, out);
}

// Round 17
// 565.985 us; speedup vs baseline: 1.0473x; 1.0092x over previous
//
#include <hip/hip_runtime.h>
#include <math.h>

#define NN 4096
#define DIM 784
#define K62 62
#define CAP 160
#define NEED 80u

typedef __attribute__((ext_vector_type(8))) short bf16x8;
typedef __attribute__((ext_vector_type(4))) float f32x4;

__device__ __forceinline__ unsigned short f2bf(float f) {
    unsigned u = __float_as_uint(f);
    return (unsigned short)((u + 0x7FFFu + ((u >> 16) & 1u)) >> 16);   // RNE
}

// ---------------- prep (R25-proven): fused sqnorm + bf16 conversion — one pass over x ----------------
__global__ __launch_bounds__(256) void k_prep(const float* __restrict__ x, double* __restrict__ sqnd,
                                              float* __restrict__ sqnf, unsigned short* __restrict__ xb) {
    int r = blockIdx.x * 4 + (threadIdx.x >> 6);
    int lane = threadIdx.x & 63;
    const float* xr = x + (size_t)r * DIM;
    unsigned short* xbr = xb + (size_t)r * 800;
    double s = 0.0;
    for (int k = lane; k < 800; k += 64) {
        if (k < DIM) {
            float v = xr[k];
            s = fma((double)v, (double)v, s);
            xbr[k] = f2bf(v);
        } else {
            xbr[k] = 0;
        }
    }
    for (int o = 32; o > 0; o >>= 1) s += __shfl_down(s, o);
    if (lane == 0) { sqnd[r] = s; sqnf[r] = (float)s; }
}

#define F4C(v, i) ((i) == 0 ? (v).x : (i) == 1 ? (v).y : (i) == 2 ? (v).z : (v).w)

// ---------------- MFMA gram (R23-proven): bf16 16x16x32, direct-global fragments, 16-bit keys ----------------
__global__ __launch_bounds__(256, 2) void k_gram_mfma(const unsigned short* __restrict__ xb,
                                                      const float* __restrict__ sqnf,
                                                      unsigned short* __restrict__ Dm16) {
    __shared__ unsigned short Cs16[64 * 72];
    int t = threadIdx.x;
    int id = blockIdx.x;
    int bi = (int)((sqrtf(8.f * (float)id + 1.f) - 1.f) * 0.5f);
    while ((bi + 1) * (bi + 2) / 2 <= id) ++bi;
    while (bi * (bi + 1) / 2 > id) --bi;
    int bj = id - bi * (bi + 1) / 2;
    int i0 = bi * 128, j0 = bj * 128;
    int wv = t >> 6, ln = t & 63;
    int l16 = ln & 15, kg = ln >> 4;

    f32x4 acc[2][8];
    #pragma unroll
    for (int rt = 0; rt < 2; ++rt)
    #pragma unroll
    for (int ct = 0; ct < 8; ++ct)
    #pragma unroll
    for (int e = 0; e < 4; ++e) acc[rt][ct][e] = 0.f;

    const unsigned short* arow0 = xb + (size_t)(i0 + wv * 32 + l16) * 800 + kg * 8;
    const unsigned short* arow1 = arow0 + 16 * 800;
    const unsigned short* brow  = xb + (size_t)(j0 + l16) * 800 + kg * 8;

    for (int ks = 0; ks < 25; ++ks) {
        bf16x8 a0 = *(const bf16x8*)(arow0 + ks * 32);
        bf16x8 a1 = *(const bf16x8*)(arow1 + ks * 32);
        #pragma unroll
        for (int ct = 0; ct < 8; ++ct) {
            bf16x8 b = *(const bf16x8*)(brow + (size_t)ct * 16 * 800 + ks * 32);
            acc[0][ct] = __builtin_amdgcn_mfma_f32_16x16x32_bf16(a0, b, acc[0][ct], 0, 0, 0);
            acc[1][ct] = __builtin_amdgcn_mfma_f32_16x16x32_bf16(a1, b, acc[1][ct], 0, 0, 0);
        }
    }
    // epilogue: d^2 keys. D[row=(kg*4+j)][col=l16] per 16x16 tile (m89 layout).
    #pragma unroll
    for (int rt = 0; rt < 2; ++rt) {
        int gr0 = i0 + wv * 32 + rt * 16 + kg * 4;
        #pragma unroll
        for (int ct = 0; ct < 8; ++ct) {
            int gc = j0 + ct * 16 + l16;
            float sj = sqnf[gc];
            #pragma unroll
            for (int j = 0; j < 4; ++j) {
                float d2 = fmaxf(sqnf[gr0 + j] + sj - 2.f * acc[rt][ct][j], 1e-12f);
                Dm16[(size_t)(gr0 + j) * NN + gc] = (unsigned short)(__float_as_uint(d2) >> 16);
            }
        }
    }
    // mirror: read tile back (L2-hot), transpose via Cs16, write coalesced.
    if (bi != bj) {
        for (int qr = 0; qr < 2; ++qr)
        for (int qc = 0; qc < 2; ++qc) {
            __syncthreads();
            #pragma unroll
            for (int g = 0; g < 2; ++g) {
                int idx = t + g * 256;
                int a = idx >> 3, c8 = idx & 7;
                uint4 v = *(const uint4*)&Dm16[(size_t)(i0 + qr * 64 + a) * NN + j0 + qc * 64 + c8 * 8];
                Cs16[(c8 * 8 + 0) * 72 + a] = (unsigned short)(v.x);
                Cs16[(c8 * 8 + 1) * 72 + a] = (unsigned short)(v.x >> 16);
                Cs16[(c8 * 8 + 2) * 72 + a] = (unsigned short)(v.y);
                Cs16[(c8 * 8 + 3) * 72 + a] = (unsigned short)(v.y >> 16);
                Cs16[(c8 * 8 + 4) * 72 + a] = (unsigned short)(v.z);
                Cs16[(c8 * 8 + 5) * 72 + a] = (unsigned short)(v.z >> 16);
                Cs16[(c8 * 8 + 6) * 72 + a] = (unsigned short)(v.w);
                Cs16[(c8 * 8 + 7) * 72 + a] = (unsigned short)(v.w >> 16);
            }
            __syncthreads();
            #pragma unroll
            for (int g = 0; g < 2; ++g) {
                int idx = t + g * 256;
                int a = idx >> 3, c8 = idx & 7;
                uint4 v = *(const uint4*)&Cs16[a * 72 + c8 * 8];
                *(uint4*)&Dm16[(size_t)(j0 + qc * 64 + a) * NN + i0 + qr * 64 + c8 * 8] = v;
            }
        }
    }
}

// ---------------- encoder (R27): R26 base, conv2 stride-5 scalar -> stride-12 b128 A/B ----------------
// conv2 issued 144 scalar LDS act reads/thread (stride-5 h1q is only 4B-aligned). Stride-12
// (48 B/pos, 16B-aligned) delivers the same data as 36 ds_read_b128 — a 108-instr/thread cut in
// the hottest loop. This is R18's fused-conv2 (proven correct) + R20's hoisted conv1, in the
// never-measured standalone combination. SB 17408 -> 22032 (R18 layout: h2s/c3/red/se overlays
// unchanged). Single variable vs R26. Revert trigger: dur >= 327 or WRITE_SIZE jump (spill).
__global__ __launch_bounds__(256, 4) void k_encoder(const float* __restrict__ x,
    const float* __restrict__ cw1, const float* __restrict__ cb1,
    const float* __restrict__ cw2, const float* __restrict__ cb2,
    const float* __restrict__ cw3, const float* __restrict__ cb3,
    const float* __restrict__ dw, const float* __restrict__ db,
    double* __restrict__ Enc, double* __restrict__ esqd)
{
    __shared__ __align__(16) unsigned char SB[22032];
    float*  sb1  = (float*)(SB);             // 32 f
    float*  sb2  = (float*)(SB + 128);       // 32 f
    float*  sb3  = (float*)(SB + 256);       // 16 f
    float*  sdb  = (float*)(SB + 320);       // 16 f
    float*  scw1 = (float*)(SB + 384);       // 288 f  [384,1536)
    float*  wq   = (float*)(SB + 1536);      // 1152 f [1536,6144)
    float*  simg = (float*)(SB + 6144);      // 900 f  [6144,9744)
    float*  h1q  = (float*)(SB + 9744);      // 256 pos x 12 words = 3072 f [9744,22032)
    float*  wq3  = (float*)(SB + 1536);      // conv3 weights over wq
    float*  h2s  = (float*)(SB + 6144);      // 49 x 44 f = 8624 B over simg+h1q-head (dead)
    float*  c3   = (float*)(SB + 6144);      // 784 f over dead h2s head
    double* red  = (double*)(SB + 14768);    // 256 d [14768,16816) over dead h1q mid
    double* se   = (double*)(SB + 16816);    // 16 d [16816,16944)

    int t = threadIdx.x;
    int n = blockIdx.x;
    for (int idx = t; idx < 3072; idx += 256) h1q[idx] = 0.f;
    for (int idx = t; idx < 900; idx += 256) simg[idx] = 0.f;
    __syncthreads();
    if (t < 196) {
        int row = t / 7, c4 = t % 7;
        float4 v = ((const float4*)(x + (size_t)n * DIM))[t];
        float* d = &simg[(row + 1) * 30 + 1 + c4 * 4];
        d[0] = v.x; d[1] = v.y; d[2] = v.z; d[3] = v.w;
    }
    for (int idx = t; idx < 288; idx += 256) scw1[idx] = cw1[idx];
    if (t < 32) { sb1[t] = cb1[t]; sb2[t] = cb2[t]; }
    if (t < 16) { sb3[t] = cb3[t]; sdb[t] = db[t]; }
    __syncthreads();

    int p2 = t >> 2, co8 = (t & 3) * 8;
    int py2 = p2 / 7, px2 = p2 % 7;
    int ch1 = t & 3;
    float acc[4][8];   // [dy*2+dx][q]
    if (t < 196) {
        #pragma unroll
        for (int pp = 0; pp < 4; ++pp)
        #pragma unroll
        for (int q = 0; q < 8; ++q) acc[pp][q] = sb2[co8 + q];
    }

    for (int oct = 0; oct < 8; ++oct) {
        __syncthreads();   // protect h1q/wq from previous octant's readers
        // ---- conv1 + relu + pool, weights hoisted (loop-invariant per octant) ----
        {
            int co = (oct << 2) + ch1;
            float wv[9];
            #pragma unroll
            for (int tp = 0; tp < 9; ++tp) wv[tp] = scw1[tp * 32 + co];
            float bias = sb1[co];
            for (int o = t; o < 784; o += 256) {
                int p = o >> 2;
                int py = p / 14, px = p % 14;
                float m = 0.f;
                #pragma unroll
                for (int dy = 0; dy < 2; ++dy)
                #pragma unroll
                for (int dx = 0; dx < 2; ++dx) {
                    const float* sp = &simg[(2 * py + dy + 1) * 30 + (2 * px + dx + 1)];
                    float a = bias;
                    a = fmaf(sp[-31], wv[0], a);
                    a = fmaf(sp[-30], wv[1], a);
                    a = fmaf(sp[-29], wv[2], a);
                    a = fmaf(sp[ -1], wv[3], a);
                    a = fmaf(sp[  0], wv[4], a);
                    a = fmaf(sp[  1], wv[5], a);
                    a = fmaf(sp[ 29], wv[6], a);
                    a = fmaf(sp[ 30], wv[7], a);
                    a = fmaf(sp[ 31], wv[8], a);
                    if (a < 0.f) a = 0.f;
                    if (a > m) m = a;
                }
                h1q[((py + 1) * 16 + (px + 1)) * 12 + ch1] = m;
            }
        }
        // ---- stage cw2 octant ----
        for (int w2 = t; w2 < 1152; w2 += 256) {
            int tap = w2 >> 7, k = w2 & 127;
            wq[w2] = cw2[tap * 1024 + oct * 128 + k];
        }
        __syncthreads();
        // ---- conv2 partial accumulate: b128 activations (stride 12, 16B-aligned) + b128 weights ----
        if (t < 196) {
            #pragma unroll
            for (int ky = 0; ky < 3; ++ky)
            #pragma unroll
            for (int kx = 0; kx < 3; ++kx) {
                const float* wb0 = &wq[(ky * 3 + kx) * 128 + co8];
                int rb = (2 * py2 + ky) * 16 + (2 * px2 + kx);
                float4 av00 = *(const float4*)&h1q[rb * 12];
                float4 av01 = *(const float4*)&h1q[(rb + 1) * 12];
                float4 av10 = *(const float4*)&h1q[(rb + 16) * 12];
                float4 av11 = *(const float4*)&h1q[(rb + 17) * 12];
                #pragma unroll
                for (int ci = 0; ci < 4; ++ci) {
                    float4 wA = *(const float4*)(wb0 + ci * 32);
                    float4 wB = *(const float4*)(wb0 + ci * 32 + 4);
                    float v00 = F4C(av00, ci), v01 = F4C(av01, ci);
                    float v10 = F4C(av10, ci), v11 = F4C(av11, ci);
                    acc[0][0] = fmaf(v00, wA.x, acc[0][0]); acc[0][1] = fmaf(v00, wA.y, acc[0][1]);
                    acc[0][2] = fmaf(v00, wA.z, acc[0][2]); acc[0][3] = fmaf(v00, wA.w, acc[0][3]);
                    acc[0][4] = fmaf(v00, wB.x, acc[0][4]); acc[0][5] = fmaf(v00, wB.y, acc[0][5]);
                    acc[0][6] = fmaf(v00, wB.z, acc[0][6]); acc[0][7] = fmaf(v00, wB.w, acc[0][7]);
                    acc[1][0] = fmaf(v01, wA.x, acc[1][0]); acc[1][1] = fmaf(v01, wA.y, acc[1][1]);
                    acc[1][2] = fmaf(v01, wA.z, acc[1][2]); acc[1][3] = fmaf(v01, wA.w, acc[1][3]);
                    acc[1][4] = fmaf(v01, wB.x, acc[1][4]); acc[1][5] = fmaf(v01, wB.y, acc[1][5]);
                    acc[1][6] = fmaf(v01, wB.z, acc[1][6]); acc[1][7] = fmaf(v01, wB.w, acc[1][7]);
                    acc[2][0] = fmaf(v10, wA.x, acc[2][0]); acc[2][1] = fmaf(v10, wA.y, acc[2][1]);
                    acc[2][2] = fmaf(v10, wA.z, acc[2][2]); acc[2][3] = fmaf(v10, wA.w, acc[2][3]);
                    acc[2][4] = fmaf(v10, wB.x, acc[2][4]); acc[2][5] = fmaf(v10, wB.y, acc[2][5]);
                    acc[2][6] = fmaf(v10, wB.z, acc[2][6]); acc[2][7] = fmaf(v10, wB.w, acc[2][7]);
                    acc[3][0] = fmaf(v11, wA.x, acc[3][0]); acc[3][1] = fmaf(v11, wA.y, acc[3][1]);
                    acc[3][2] = fmaf(v11, wA.z, acc[3][2]); acc[3][3] = fmaf(v11, wA.w, acc[3][3]);
                    acc[3][4] = fmaf(v11, wB.x, acc[3][4]); acc[3][5] = fmaf(v11, wB.y, acc[3][5]);
                    acc[3][6] = fmaf(v11, wB.z, acc[3][6]); acc[3][7] = fmaf(v11, wB.w, acc[3][7]);
                }
            }
        }
    }
    __syncthreads();   // last conv2 reads of h1q/wq done; h2s overlay becomes legal
    if (t < 196) {
        float mm[8];
        #pragma unroll
        for (int q = 0; q < 8; ++q) {
            float m = 0.f;
            #pragma unroll
            for (int pp = 0; pp < 4; ++pp) {
                float a = acc[pp][q];
                if (a < 0.f) a = 0.f;
                if (a > m) m = a;
            }
            mm[q] = m;
        }
        *(float4*)&h2s[p2 * 44 + co8]     = make_float4(mm[0], mm[1], mm[2], mm[3]);
        *(float4*)&h2s[p2 * 44 + co8 + 4] = make_float4(mm[4], mm[5], mm[6], mm[7]);
    }
    float a0 = 0.f, a1 = 0.f, a2 = 0.f, a3 = 0.f;
    int p3 = t >> 2, co4 = (t & 3) * 4;
    int py3 = p3 / 7, px3 = p3 % 7;
    if (t < 196) {
        a0 = sb3[co4]; a1 = sb3[co4 + 1];
        a2 = sb3[co4 + 2]; a3 = sb3[co4 + 3];
    }
    for (int qq = 0; qq < 4; ++qq) {
        __syncthreads();
        for (int w2 = t; w2 < 1152; w2 += 256) {
            int tap = w2 >> 7, k = w2 & 127;
            wq3[w2] = cw3[tap * 512 + qq * 128 + k];
        }
        __syncthreads();
        if (t < 196) {
            for (int ky = 0; ky < 3; ++ky) {
                int iy = py3 + ky - 1; if ((unsigned)iy >= 7u) continue;
                for (int kx = 0; kx < 3; ++kx) {
                    int ix = px3 + kx - 1; if ((unsigned)ix >= 7u) continue;
                    const float* hp = &h2s[(iy * 7 + ix) * 44 + qq * 8];
                    float4 h0 = *(const float4*)hp;
                    float4 h1 = *(const float4*)(hp + 4);
                    const float* wp = &wq3[(ky * 3 + kx) * 128 + co4];
                    #pragma unroll
                    for (int ci = 0; ci < 8; ++ci) {
                        float av = (ci < 4) ? F4C(h0, ci) : F4C(h1, ci - 4);
                        float4 wv = *(const float4*)(wp + ci * 16);
                        a0 = fmaf(av, wv.x, a0); a1 = fmaf(av, wv.y, a1);
                        a2 = fmaf(av, wv.z, a2); a3 = fmaf(av, wv.w, a3);
                    }
                }
            }
        }
    }
    __syncthreads();   // all conv3 reads of h2s done -> c3 may overwrite h2s head
    if (t < 196) {
        float r0 = a0 > 0.f ? a0 : 0.f, r1 = a1 > 0.f ? a1 : 0.f;
        float r2 = a2 > 0.f ? a2 : 0.f, r3 = a3 > 0.f ? a3 : 0.f;
        *(float4*)&c3[p3 * 16 + co4] = make_float4(r0, r1, r2, r3);
    }
    __syncthreads();
    {
        int part = t >> 4, o = t & 15, j0 = part * 49;
        double s = 0.0;
        for (int j = 0; j < 49; ++j) s = fma((double)c3[j0 + j], (double)dw[(size_t)(j0 + j) * 16 + o], s);
        red[part * 16 + o] = s;
    }
    __syncthreads();
    if (t < 16) {
        double e = (double)sdb[t];
        for (int q = 0; q < 16; ++q) e += red[q * 16 + t];
        Enc[(size_t)n * 16 + t] = e;
        se[t] = e;
    }
    __syncthreads();
    if (t == 0) {
        double s = 0.0;
        for (int q = 0; q < 16; ++q) s += se[q] * se[q];
        esqd[n] = s;
    }
}

// ---------------- selection (R23-proven): 16-bit key scan, NEED=80, 16-lane-group refine ----------------
__global__ __launch_bounds__(256) void k_topsel(const unsigned short* __restrict__ Dm16,
                                                const double* __restrict__ sqnd,
                                                const float* __restrict__ x,
                                                double* __restrict__ topvd, int* __restrict__ topi) {
    __shared__ float xi[DIM];
    __shared__ unsigned wsum[8];
    __shared__ int cj[CAP];
    __shared__ double cvd[CAP];
    __shared__ unsigned ncnt;
    int i = blockIdx.x, t = threadIdx.x;
    const unsigned* drow = (const unsigned*)(Dm16 + (size_t)i * NN);   // 2048 uints = 4096 keys
    unsigned uk[8];
    #pragma unroll
    for (int s = 0; s < 8; ++s) {
        int wd = t + s * 256;
        unsigned u = drow[wd];
        if (2 * wd == i)     u &= 0xFFFF0000u;   // mask self (low key)
        if (2 * wd + 1 == i) u &= 0x0000FFFFu;   // mask self (high key)
        uk[s] = u;
    }
    if (t < 196) ((float4*)xi)[t] = ((const float4*)(x + (size_t)i * DIM))[t];
    if (t == 0) ncnt = 0;
    int lane = t & 63, w = t >> 6;
    unsigned lo = 0u, hi = 0xFFFFu;
    for (int it = 0; it < 16; ++it) {
        unsigned mid = (lo + hi + 1u) >> 1;
        unsigned cnt = 0;
        #pragma unroll
        for (int s = 0; s < 8; ++s) {
            cnt += ((uk[s] & 0xFFFFu) >= mid) ? 1u : 0u;
            cnt += ((uk[s] >> 16) >= mid) ? 1u : 0u;
        }
        #pragma unroll
        for (int off = 32; off > 0; off >>= 1) cnt += __shfl_down(cnt, off);
        if (lane == 0) wsum[(it & 1) * 4 + w] = cnt;
        __syncthreads();
        int bb = (it & 1) * 4;
        unsigned tot = wsum[bb] + wsum[bb + 1] + wsum[bb + 2] + wsum[bb + 3];
        if (tot >= NEED) lo = mid; else hi = mid - 1u;
    }
    unsigned prefix = lo;   // 16-bit key of the NEED-th-largest distance
    #pragma unroll
    for (int s = 0; s < 8; ++s) {
        int wd = t + s * 256;
        if ((uk[s] & 0xFFFFu) >= prefix) {
            unsigned p = atomicAdd(&ncnt, 1u);
            if (p < CAP) cj[p] = 2 * wd;
        }
        if ((uk[s] >> 16) >= prefix) {
            unsigned p = atomicAdd(&ncnt, 1u);
            if (p < CAP) cj[p] = 2 * wd + 1;
        }
    }
    __syncthreads();
    int ncand = min((int)ncnt, CAP);
    double sqi_d = sqnd[i];
    const float4* xi4 = (const float4*)xi;
    int g = t >> 4, gl = t & 15;   // 16 groups of 16 lanes: 16 gathers in flight
    for (int c = g; c < ncand; c += 16) {
        const float4* xj4 = (const float4*)(x + (size_t)cj[c] * DIM);
        double s = 0.0;
        for (int k = gl; k < 196; k += 16) {
            float4 a = xi4[k]; float4 b = xj4[k];
            s = fma((double)a.x, (double)b.x, s);
            s = fma((double)a.y, (double)b.y, s);
            s = fma((double)a.z, (double)b.z, s);
            s = fma((double)a.w, (double)b.w, s);
        }
        #pragma unroll
        for (int o = 8; o > 0; o >>= 1) s += __shfl_down(s, o, 16);
        if (gl == 0) cvd[c] = sqrt(fmax(sqi_d + sqnd[cj[c]] - 2.0 * s, 1e-12));
    }
    __syncthreads();
    if (t < ncand) {
        double v = cvd[t]; int jj = cj[t];
        int r = 0;
        for (int c2 = 0; c2 < ncand; ++c2) {
            double v2 = cvd[c2];
            if (v2 > v || (v2 == v && cj[c2] < jj)) ++r;
        }
        if (r >= 1 && r < 63) {
            topvd[(size_t)i * K62 + r - 1] = v;
            topi[(size_t)i * K62 + r - 1] = jj;
        }
    }
}

// ---------------- encoded distances + ratio partial ----------------
__global__ __launch_bounds__(256) void k_ratio(const double* __restrict__ Enc, const double* __restrict__ esqd,
                                               const double* __restrict__ topvd, const int* __restrict__ topi,
                                               double* __restrict__ vencd, double* __restrict__ Sp) {
    __shared__ double wp[4];
    int r = blockIdx.x * 4 + (threadIdx.x >> 6);
    int lane = threadIdx.x & 63, w = threadIdx.x >> 6;
    double ratio = 0.0;
    if (lane < K62) {
        int j = topi[(size_t)r * K62 + lane];
        const double* Er = Enc + (size_t)r * 16;
        const double* Ej = Enc + (size_t)j * 16;
        double dot = 0.0;
        #pragma unroll
        for (int q = 0; q < 16; ++q) dot = fma(Er[q], Ej[q], dot);
        double ve = sqrt(fmax(esqd[r] + esqd[j] - 2.0 * dot, 1e-12));
        vencd[(size_t)r * K62 + lane] = ve;
        ratio = topvd[(size_t)r * K62 + lane] / ve;
    }
    for (int o = 32; o > 0; o >>= 1) ratio += __shfl_down(ratio, o);
    if (lane == 0) wp[w] = ratio;
    __syncthreads();
    if (threadIdx.x == 0) Sp[blockIdx.x] = wp[0] + wp[1] + wp[2] + wp[3];
}

// ---------------- loss (merged Sp reduce; identical arithmetic order) ----------------
__global__ __launch_bounds__(256) void k_loss(const double* __restrict__ topvd, const double* __restrict__ vencd,
                                              const double* __restrict__ Sp, double* __restrict__ Lp) {
    __shared__ double wp[4];
    __shared__ double wq2[4];
    int t = threadIdx.x;
    int lane = t & 63, w = t >> 6;
    double sp = Sp[t] + Sp[t + 256] + Sp[t + 512] + Sp[t + 768];
    for (int o = 32; o > 0; o >>= 1) sp += __shfl_down(sp, o);
    if (lane == 0) wp[w] = sp;
    __syncthreads();
    double m = (wp[0] + wp[1] + wp[2] + wp[3]) * (1.0 / (4096.0 * 62.0));
    int r = blockIdx.x * 4 + w;
    double v = -1.0;
    if (lane < K62) {
        double d = topvd[(size_t)r * K62 + lane] - m * vencd[(size_t)r * K62 + lane];
        v = d * d;
    }
    for (int o = 32; o > 0; o >>= 1) { double ov = __shfl_down(v, o); v = (ov > v) ? ov : v; }
    if (lane == 0) wq2[w] = v;
    __syncthreads();
    if (t == 0) Lp[blockIdx.x] = wq2[0] + wq2[1] + wq2[2] + wq2[3];
}

__global__ __launch_bounds__(256) void k_final(const double* __restrict__ Lp, float* __restrict__ out) {
    __shared__ double wp[4];
    int t = threadIdx.x, lane = t & 63, w = t >> 6;
    double s = Lp[t] + Lp[t + 256] + Lp[t + 512] + Lp[t + 768];
    for (int o = 32; o > 0; o >>= 1) s += __shfl_down(s, o);
    if (lane == 0) wp[w] = s;
    __syncthreads();
    if (t == 0) out[0] = (float)((wp[0] + wp[1] + wp[2] + wp[3]) * (1.0 / 4096.0));
}

extern "C" void kernel_launch(void* const* d_in, const int* in_sizes, int n_in,
                              void* d_out, int out_size, void* d_ws, size_t ws_size,
                              hipStream_t stream) {
    const float* x   = (const float*)d_in[0];
    const float* cw1 = (const float*)d_in[1];
    const float* cb1 = (const float*)d_in[2];
    const float* cw2 = (const float*)d_in[3];
    const float* cb2 = (const float*)d_in[4];
    const float* cw3 = (const float*)d_in[5];
    const float* cb3 = (const float*)d_in[6];
    const float* dw  = (const float*)d_in[7];
    const float* db  = (const float*)d_in[8];

    char* wsb = (char*)d_ws;
    unsigned short* Dm16 = (unsigned short*)wsb;           // 4096*4096*2 = 33,554,432 B
    double* Enc   = (double*)(wsb + 33554432);             // 65,536 d
    double* esqd  = (double*)(wsb + 34078720);             // 4,096 d
    double* sqnd  = (double*)(wsb + 34111488);             // 4,096 d
    float*  sqnf  = (float*)(wsb + 34144256);              // 4,096 f
    double* topvd = (double*)(wsb + 34160640);             // 253,952 d
    double* vencd = (double*)(wsb + 36192256);             // 253,952 d
    int*    topi  = (int*)(wsb + 38223872);                // 253,952 i
    double* Sp    = (double*)(wsb + 39239680);             // 1,024 d
    double* Lp    = (double*)(wsb + 39247872);             // 1,024 d
    unsigned short* xb = (unsigned short*)(wsb + 39256064);// 4096*800 bf16 = 6,553,600 B
    float*  out   = (float*)d_out;

    k_prep<<<1024, 256, 0, stream>>>(x, sqnd, sqnf, xb);
    k_gram_mfma<<<528, 256, 0, stream>>>(xb, sqnf, Dm16);
    k_encoder<<<4096, 256, 0, stream>>>(x, cw1, cb1, cw2, cb2, cw3, cb3, dw, db, Enc, esqd);
    k_topsel<<<4096, 256, 0, stream>>>(Dm16, sqnd, x, topvd, topi);
    k_ratio<<<1024, 256, 0, stream>>>(Enc, esqd, topvd, topi, vencd, Sp);
    k_loss<<<1024, 256, 0, stream>>>(topvd, vencd, Sp, Lp);
    k_final<<<1, 256, 0, stream>>>(Lp, out);
}

// Round 18
// 533.802 us; speedup vs baseline: 1.1105x; 1.0603x over previous
//
#include <hip/hip_runtime.h>
#include <math.h>

#define NN 4096
#define DIM 784
#define K62 62
#define CAP 160
#define NEED 80u

typedef __attribute__((ext_vector_type(8))) short bf16x8;
typedef __attribute__((ext_vector_type(4))) float f32x4;

__device__ __forceinline__ unsigned short f2bf(float f) {
    unsigned u = __float_as_uint(f);
    return (unsigned short)((u + 0x7FFFu + ((u >> 16) & 1u)) >> 16);   // RNE
}

// ---------------- prep (R25-proven): fused sqnorm + bf16 conversion — one pass over x ----------------
__global__ __launch_bounds__(256) void k_prep(const float* __restrict__ x, double* __restrict__ sqnd,
                                              float* __restrict__ sqnf, unsigned short* __restrict__ xb) {
    int r = blockIdx.x * 4 + (threadIdx.x >> 6);
    int lane = threadIdx.x & 63;
    const float* xr = x + (size_t)r * DIM;
    unsigned short* xbr = xb + (size_t)r * 800;
    double s = 0.0;
    for (int k = lane; k < 800; k += 64) {
        if (k < DIM) {
            float v = xr[k];
            s = fma((double)v, (double)v, s);
            xbr[k] = f2bf(v);
        } else {
            xbr[k] = 0;
        }
    }
    for (int o = 32; o > 0; o >>= 1) s += __shfl_down(s, o);
    if (lane == 0) { sqnd[r] = s; sqnf[r] = (float)s; }
}

#define F4C(v, i) ((i) == 0 ? (v).x : (i) == 1 ? (v).y : (i) == 2 ? (v).z : (v).w)

// ---------------- MFMA gram (R28: B-tile LDS-staged) ----------------
// R27 traffic model: all 4 waves re-loaded the SAME B fragments from L3 (B depends on ct/ks, not
// wave) -> ~820 KB/block of 4x-redundant B traffic, ~540 MB chip-wide vs the 6.5 MB L3-resident
// xb ~= the inferred ~110 us gram time. Fix: per ks, cooperatively stage the 128x32 bf16 B-chunk
// (8 KB; 32 B/thread) into LDS once; all waves ds_read fragments. Row stride padded to 40 ushorts
// (80 B): read banks 20*l16 mod 32 = {0,20,8,28,16,4,24,12} 2-way = free; 16B-aligned. B traffic
// /4; A-loads, MFMA core, epilogue, mirror unchanged -> keys bit-identical.
__global__ __launch_bounds__(256, 2) void k_gram_mfma(const unsigned short* __restrict__ xb,
                                                      const float* __restrict__ sqnf,
                                                      unsigned short* __restrict__ Dm16) {
    __shared__ __align__(16) unsigned char GB[10240];
    unsigned short* Bs   = (unsigned short*)GB;   // 128 rows x 40 ushorts (32 data + 8 pad) = 10240 B
    unsigned short* Cs16 = (unsigned short*)GB;   // 64 x 72 = 9216 B overlay (after K loop)
    int t = threadIdx.x;
    int id = blockIdx.x;
    int bi = (int)((sqrtf(8.f * (float)id + 1.f) - 1.f) * 0.5f);
    while ((bi + 1) * (bi + 2) / 2 <= id) ++bi;
    while (bi * (bi + 1) / 2 > id) --bi;
    int bj = id - bi * (bi + 1) / 2;
    int i0 = bi * 128, j0 = bj * 128;
    int wv = t >> 6, ln = t & 63;
    int l16 = ln & 15, kg = ln >> 4;

    f32x4 acc[2][8];
    #pragma unroll
    for (int rt = 0; rt < 2; ++rt)
    #pragma unroll
    for (int ct = 0; ct < 8; ++ct)
    #pragma unroll
    for (int e = 0; e < 4; ++e) acc[rt][ct][e] = 0.f;

    const unsigned short* arow0 = xb + (size_t)(i0 + wv * 32 + l16) * 800 + kg * 8;
    const unsigned short* arow1 = arow0 + 16 * 800;
    int brt = t >> 1, bh = t & 1;                 // B stage: row, 16-ushort half
    const unsigned short* bsrc = xb + (size_t)(j0 + brt) * 800 + bh * 16;
    unsigned short* bdst = Bs + brt * 40 + bh * 16;

    for (int ks = 0; ks < 25; ++ks) {
        __syncthreads();   // previous iteration's Bs readers done
        *(uint4*)bdst       = *(const uint4*)(bsrc + ks * 32);
        *(uint4*)(bdst + 8) = *(const uint4*)(bsrc + ks * 32 + 8);
        __syncthreads();
        bf16x8 a0 = *(const bf16x8*)(arow0 + ks * 32);
        bf16x8 a1 = *(const bf16x8*)(arow1 + ks * 32);
        #pragma unroll
        for (int ct = 0; ct < 8; ++ct) {
            bf16x8 b = *(const bf16x8*)&Bs[(ct * 16 + l16) * 40 + kg * 8];
            acc[0][ct] = __builtin_amdgcn_mfma_f32_16x16x32_bf16(a0, b, acc[0][ct], 0, 0, 0);
            acc[1][ct] = __builtin_amdgcn_mfma_f32_16x16x32_bf16(a1, b, acc[1][ct], 0, 0, 0);
        }
    }
    // epilogue: d^2 keys. D[row=(kg*4+j)][col=l16] per 16x16 tile (m89 layout).
    #pragma unroll
    for (int rt = 0; rt < 2; ++rt) {
        int gr0 = i0 + wv * 32 + rt * 16 + kg * 4;
        #pragma unroll
        for (int ct = 0; ct < 8; ++ct) {
            int gc = j0 + ct * 16 + l16;
            float sj = sqnf[gc];
            #pragma unroll
            for (int j = 0; j < 4; ++j) {
                float d2 = fmaxf(sqnf[gr0 + j] + sj - 2.f * acc[rt][ct][j], 1e-12f);
                Dm16[(size_t)(gr0 + j) * NN + gc] = (unsigned short)(__float_as_uint(d2) >> 16);
            }
        }
    }
    // mirror: read tile back (L2-hot), transpose via Cs16 (overlays Bs; first barrier protects), write coalesced.
    if (bi != bj) {
        for (int qr = 0; qr < 2; ++qr)
        for (int qc = 0; qc < 2; ++qc) {
            __syncthreads();
            #pragma unroll
            for (int g = 0; g < 2; ++g) {
                int idx = t + g * 256;
                int a = idx >> 3, c8 = idx & 7;
                uint4 v = *(const uint4*)&Dm16[(size_t)(i0 + qr * 64 + a) * NN + j0 + qc * 64 + c8 * 8];
                Cs16[(c8 * 8 + 0) * 72 + a] = (unsigned short)(v.x);
                Cs16[(c8 * 8 + 1) * 72 + a] = (unsigned short)(v.x >> 16);
                Cs16[(c8 * 8 + 2) * 72 + a] = (unsigned short)(v.y);
                Cs16[(c8 * 8 + 3) * 72 + a] = (unsigned short)(v.y >> 16);
                Cs16[(c8 * 8 + 4) * 72 + a] = (unsigned short)(v.z);
                Cs16[(c8 * 8 + 5) * 72 + a] = (unsigned short)(v.z >> 16);
                Cs16[(c8 * 8 + 6) * 72 + a] = (unsigned short)(v.w);
                Cs16[(c8 * 8 + 7) * 72 + a] = (unsigned short)(v.w >> 16);
            }
            __syncthreads();
            #pragma unroll
            for (int g = 0; g < 2; ++g) {
                int idx = t + g * 256;
                int a = idx >> 3, c8 = idx & 7;
                uint4 v = *(const uint4*)&Cs16[a * 72 + c8 * 8];
                *(uint4*)&Dm16[(size_t)(j0 + qc * 64 + a) * NN + i0 + qr * 64 + c8 * 8] = v;
            }
        }
    }
}

// ---------------- encoder (R27-proven: stride-12 b128 conv2, hoisted conv1 weights) ----------------
__global__ __launch_bounds__(256, 4) void k_encoder(const float* __restrict__ x,
    const float* __restrict__ cw1, const float* __restrict__ cb1,
    const float* __restrict__ cw2, const float* __restrict__ cb2,
    const float* __restrict__ cw3, const float* __restrict__ cb3,
    const float* __restrict__ dw, const float* __restrict__ db,
    double* __restrict__ Enc, double* __restrict__ esqd)
{
    __shared__ __align__(16) unsigned char SB[22032];
    float*  sb1  = (float*)(SB);             // 32 f
    float*  sb2  = (float*)(SB + 128);       // 32 f
    float*  sb3  = (float*)(SB + 256);       // 16 f
    float*  sdb  = (float*)(SB + 320);       // 16 f
    float*  scw1 = (float*)(SB + 384);       // 288 f  [384,1536)
    float*  wq   = (float*)(SB + 1536);      // 1152 f [1536,6144)
    float*  simg = (float*)(SB + 6144);      // 900 f  [6144,9744)
    float*  h1q  = (float*)(SB + 9744);      // 256 pos x 12 words = 3072 f [9744,22032)
    float*  wq3  = (float*)(SB + 1536);      // conv3 weights over wq
    float*  h2s  = (float*)(SB + 6144);      // 49 x 44 f = 8624 B over simg+h1q-head (dead)
    float*  c3   = (float*)(SB + 6144);      // 784 f over dead h2s head
    double* red  = (double*)(SB + 14768);    // 256 d [14768,16816) over dead h1q mid
    double* se   = (double*)(SB + 16816);    // 16 d [16816,16944)

    int t = threadIdx.x;
    int n = blockIdx.x;
    for (int idx = t; idx < 3072; idx += 256) h1q[idx] = 0.f;
    for (int idx = t; idx < 900; idx += 256) simg[idx] = 0.f;
    __syncthreads();
    if (t < 196) {
        int row = t / 7, c4 = t % 7;
        float4 v = ((const float4*)(x + (size_t)n * DIM))[t];
        float* d = &simg[(row + 1) * 30 + 1 + c4 * 4];
        d[0] = v.x; d[1] = v.y; d[2] = v.z; d[3] = v.w;
    }
    for (int idx = t; idx < 288; idx += 256) scw1[idx] = cw1[idx];
    if (t < 32) { sb1[t] = cb1[t]; sb2[t] = cb2[t]; }
    if (t < 16) { sb3[t] = cb3[t]; sdb[t] = db[t]; }
    __syncthreads();

    int p2 = t >> 2, co8 = (t & 3) * 8;
    int py2 = p2 / 7, px2 = p2 % 7;
    int ch1 = t & 3;
    float acc[4][8];   // [dy*2+dx][q]
    if (t < 196) {
        #pragma unroll
        for (int pp = 0; pp < 4; ++pp)
        #pragma unroll
        for (int q = 0; q < 8; ++q) acc[pp][q] = sb2[co8 + q];
    }

    for (int oct = 0; oct < 8; ++oct) {
        __syncthreads();   // protect h1q/wq from previous octant's readers
        {
            int co = (oct << 2) + ch1;
            float wv[9];
            #pragma unroll
            for (int tp = 0; tp < 9; ++tp) wv[tp] = scw1[tp * 32 + co];
            float bias = sb1[co];
            for (int o = t; o < 784; o += 256) {
                int p = o >> 2;
                int py = p / 14, px = p % 14;
                float m = 0.f;
                #pragma unroll
                for (int dy = 0; dy < 2; ++dy)
                #pragma unroll
                for (int dx = 0; dx < 2; ++dx) {
                    const float* sp = &simg[(2 * py + dy + 1) * 30 + (2 * px + dx + 1)];
                    float a = bias;
                    a = fmaf(sp[-31], wv[0], a);
                    a = fmaf(sp[-30], wv[1], a);
                    a = fmaf(sp[-29], wv[2], a);
                    a = fmaf(sp[ -1], wv[3], a);
                    a = fmaf(sp[  0], wv[4], a);
                    a = fmaf(sp[  1], wv[5], a);
                    a = fmaf(sp[ 29], wv[6], a);
                    a = fmaf(sp[ 30], wv[7], a);
                    a = fmaf(sp[ 31], wv[8], a);
                    if (a < 0.f) a = 0.f;
                    if (a > m) m = a;
                }
                h1q[((py + 1) * 16 + (px + 1)) * 12 + ch1] = m;
            }
        }
        for (int w2 = t; w2 < 1152; w2 += 256) {
            int tap = w2 >> 7, k = w2 & 127;
            wq[w2] = cw2[tap * 1024 + oct * 128 + k];
        }
        __syncthreads();
        if (t < 196) {
            #pragma unroll
            for (int ky = 0; ky < 3; ++ky)
            #pragma unroll
            for (int kx = 0; kx < 3; ++kx) {
                const float* wb0 = &wq[(ky * 3 + kx) * 128 + co8];
                int rb = (2 * py2 + ky) * 16 + (2 * px2 + kx);
                float4 av00 = *(const float4*)&h1q[rb * 12];
                float4 av01 = *(const float4*)&h1q[(rb + 1) * 12];
                float4 av10 = *(const float4*)&h1q[(rb + 16) * 12];
                float4 av11 = *(const float4*)&h1q[(rb + 17) * 12];
                #pragma unroll
                for (int ci = 0; ci < 4; ++ci) {
                    float4 wA = *(const float4*)(wb0 + ci * 32);
                    float4 wB = *(const float4*)(wb0 + ci * 32 + 4);
                    float v00 = F4C(av00, ci), v01 = F4C(av01, ci);
                    float v10 = F4C(av10, ci), v11 = F4C(av11, ci);
                    acc[0][0] = fmaf(v00, wA.x, acc[0][0]); acc[0][1] = fmaf(v00, wA.y, acc[0][1]);
                    acc[0][2] = fmaf(v00, wA.z, acc[0][2]); acc[0][3] = fmaf(v00, wA.w, acc[0][3]);
                    acc[0][4] = fmaf(v00, wB.x, acc[0][4]); acc[0][5] = fmaf(v00, wB.y, acc[0][5]);
                    acc[0][6] = fmaf(v00, wB.z, acc[0][6]); acc[0][7] = fmaf(v00, wB.w, acc[0][7]);
                    acc[1][0] = fmaf(v01, wA.x, acc[1][0]); acc[1][1] = fmaf(v01, wA.y, acc[1][1]);
                    acc[1][2] = fmaf(v01, wA.z, acc[1][2]); acc[1][3] = fmaf(v01, wA.w, acc[1][3]);
                    acc[1][4] = fmaf(v01, wB.x, acc[1][4]); acc[1][5] = fmaf(v01, wB.y, acc[1][5]);
                    acc[1][6] = fmaf(v01, wB.z, acc[1][6]); acc[1][7] = fmaf(v01, wB.w, acc[1][7]);
                    acc[2][0] = fmaf(v10, wA.x, acc[2][0]); acc[2][1] = fmaf(v10, wA.y, acc[2][1]);
                    acc[2][2] = fmaf(v10, wA.z, acc[2][2]); acc[2][3] = fmaf(v10, wA.w, acc[2][3]);
                    acc[2][4] = fmaf(v10, wB.x, acc[2][4]); acc[2][5] = fmaf(v10, wB.y, acc[2][5]);
                    acc[2][6] = fmaf(v10, wB.z, acc[2][6]); acc[2][7] = fmaf(v10, wB.w, acc[2][7]);
                    acc[3][0] = fmaf(v11, wA.x, acc[3][0]); acc[3][1] = fmaf(v11, wA.y, acc[3][1]);
                    acc[3][2] = fmaf(v11, wA.z, acc[3][2]); acc[3][3] = fmaf(v11, wA.w, acc[3][3]);
                    acc[3][4] = fmaf(v11, wB.x, acc[3][4]); acc[3][5] = fmaf(v11, wB.y, acc[3][5]);
                    acc[3][6] = fmaf(v11, wB.z, acc[3][6]); acc[3][7] = fmaf(v11, wB.w, acc[3][7]);
                }
            }
        }
    }
    __syncthreads();   // last conv2 reads of h1q/wq done; h2s overlay becomes legal
    if (t < 196) {
        float mm[8];
        #pragma unroll
        for (int q = 0; q < 8; ++q) {
            float m = 0.f;
            #pragma unroll
            for (int pp = 0; pp < 4; ++pp) {
                float a = acc[pp][q];
                if (a < 0.f) a = 0.f;
                if (a > m) m = a;
            }
            mm[q] = m;
        }
        *(float4*)&h2s[p2 * 44 + co8]     = make_float4(mm[0], mm[1], mm[2], mm[3]);
        *(float4*)&h2s[p2 * 44 + co8 + 4] = make_float4(mm[4], mm[5], mm[6], mm[7]);
    }
    float a0 = 0.f, a1 = 0.f, a2 = 0.f, a3 = 0.f;
    int p3 = t >> 2, co4 = (t & 3) * 4;
    int py3 = p3 / 7, px3 = p3 % 7;
    if (t < 196) {
        a0 = sb3[co4]; a1 = sb3[co4 + 1];
        a2 = sb3[co4 + 2]; a3 = sb3[co4 + 3];
    }
    for (int qq = 0; qq < 4; ++qq) {
        __syncthreads();
        for (int w2 = t; w2 < 1152; w2 += 256) {
            int tap = w2 >> 7, k = w2 & 127;
            wq3[w2] = cw3[tap * 512 + qq * 128 + k];
        }
        __syncthreads();
        if (t < 196) {
            for (int ky = 0; ky < 3; ++ky) {
                int iy = py3 + ky - 1; if ((unsigned)iy >= 7u) continue;
                for (int kx = 0; kx < 3; ++kx) {
                    int ix = px3 + kx - 1; if ((unsigned)ix >= 7u) continue;
                    const float* hp = &h2s[(iy * 7 + ix) * 44 + qq * 8];
                    float4 h0 = *(const float4*)hp;
                    float4 h1 = *(const float4*)(hp + 4);
                    const float* wp = &wq3[(ky * 3 + kx) * 128 + co4];
                    #pragma unroll
                    for (int ci = 0; ci < 8; ++ci) {
                        float av = (ci < 4) ? F4C(h0, ci) : F4C(h1, ci - 4);
                        float4 wv = *(const float4*)(wp + ci * 16);
                        a0 = fmaf(av, wv.x, a0); a1 = fmaf(av, wv.y, a1);
                        a2 = fmaf(av, wv.z, a2); a3 = fmaf(av, wv.w, a3);
                    }
                }
            }
        }
    }
    __syncthreads();   // all conv3 reads of h2s done -> c3 may overwrite h2s head
    if (t < 196) {
        float r0 = a0 > 0.f ? a0 : 0.f, r1 = a1 > 0.f ? a1 : 0.f;
        float r2 = a2 > 0.f ? a2 : 0.f, r3 = a3 > 0.f ? a3 : 0.f;
        *(float4*)&c3[p3 * 16 + co4] = make_float4(r0, r1, r2, r3);
    }
    __syncthreads();
    {
        int part = t >> 4, o = t & 15, j0 = part * 49;
        double s = 0.0;
        for (int j = 0; j < 49; ++j) s = fma((double)c3[j0 + j], (double)dw[(size_t)(j0 + j) * 16 + o], s);
        red[part * 16 + o] = s;
    }
    __syncthreads();
    if (t < 16) {
        double e = (double)sdb[t];
        for (int q = 0; q < 16; ++q) e += red[q * 16 + t];
        Enc[(size_t)n * 16 + t] = e;
        se[t] = e;
    }
    __syncthreads();
    if (t == 0) {
        double s = 0.0;
        for (int q = 0; q < 16; ++q) s += se[q] * se[q];
        esqd[n] = s;
    }
}

// ---------------- selection (R23-proven): 16-bit key scan, NEED=80, 16-lane-group refine ----------------
__global__ __launch_bounds__(256) void k_topsel(const unsigned short* __restrict__ Dm16,
                                                const double* __restrict__ sqnd,
                                                const float* __restrict__ x,
                                                double* __restrict__ topvd, int* __restrict__ topi) {
    __shared__ float xi[DIM];
    __shared__ unsigned wsum[8];
    __shared__ int cj[CAP];
    __shared__ double cvd[CAP];
    __shared__ unsigned ncnt;
    int i = blockIdx.x, t = threadIdx.x;
    const unsigned* drow = (const unsigned*)(Dm16 + (size_t)i * NN);   // 2048 uints = 4096 keys
    unsigned uk[8];
    #pragma unroll
    for (int s = 0; s < 8; ++s) {
        int wd = t + s * 256;
        unsigned u = drow[wd];
        if (2 * wd == i)     u &= 0xFFFF0000u;   // mask self (low key)
        if (2 * wd + 1 == i) u &= 0x0000FFFFu;   // mask self (high key)
        uk[s] = u;
    }
    if (t < 196) ((float4*)xi)[t] = ((const float4*)(x + (size_t)i * DIM))[t];
    if (t == 0) ncnt = 0;
    int lane = t & 63, w = t >> 6;
    unsigned lo = 0u, hi = 0xFFFFu;
    for (int it = 0; it < 16; ++it) {
        unsigned mid = (lo + hi + 1u) >> 1;
        unsigned cnt = 0;
        #pragma unroll
        for (int s = 0; s < 8; ++s) {
            cnt += ((uk[s] & 0xFFFFu) >= mid) ? 1u : 0u;
            cnt += ((uk[s] >> 16) >= mid) ? 1u : 0u;
        }
        #pragma unroll
        for (int off = 32; off > 0; off >>= 1) cnt += __shfl_down(cnt, off);
        if (lane == 0) wsum[(it & 1) * 4 + w] = cnt;
        __syncthreads();
        int bb = (it & 1) * 4;
        unsigned tot = wsum[bb] + wsum[bb + 1] + wsum[bb + 2] + wsum[bb + 3];
        if (tot >= NEED) lo = mid; else hi = mid - 1u;
    }
    unsigned prefix = lo;   // 16-bit key of the NEED-th-largest distance
    #pragma unroll
    for (int s = 0; s < 8; ++s) {
        int wd = t + s * 256;
        if ((uk[s] & 0xFFFFu) >= prefix) {
            unsigned p = atomicAdd(&ncnt, 1u);
            if (p < CAP) cj[p] = 2 * wd;
        }
        if ((uk[s] >> 16) >= prefix) {
            unsigned p = atomicAdd(&ncnt, 1u);
            if (p < CAP) cj[p] = 2 * wd + 1;
        }
    }
    __syncthreads();
    int ncand = min((int)ncnt, CAP);
    double sqi_d = sqnd[i];
    const float4* xi4 = (const float4*)xi;
    int g = t >> 4, gl = t & 15;   // 16 groups of 16 lanes: 16 gathers in flight
    for (int c = g; c < ncand; c += 16) {
        const float4* xj4 = (const float4*)(x + (size_t)cj[c] * DIM);
        double s = 0.0;
        for (int k = gl; k < 196; k += 16) {
            float4 a = xi4[k]; float4 b = xj4[k];
            s = fma((double)a.x, (double)b.x, s);
            s = fma((double)a.y, (double)b.y, s);
            s = fma((double)a.z, (double)b.z, s);
            s = fma((double)a.w, (double)b.w, s);
        }
        #pragma unroll
        for (int o = 8; o > 0; o >>= 1) s += __shfl_down(s, o, 16);
        if (gl == 0) cvd[c] = sqrt(fmax(sqi_d + sqnd[cj[c]] - 2.0 * s, 1e-12));
    }
    __syncthreads();
    if (t < ncand) {
        double v = cvd[t]; int jj = cj[t];
        int r = 0;
        for (int c2 = 0; c2 < ncand; ++c2) {
            double v2 = cvd[c2];
            if (v2 > v || (v2 == v && cj[c2] < jj)) ++r;
        }
        if (r >= 1 && r < 63) {
            topvd[(size_t)i * K62 + r - 1] = v;
            topi[(size_t)i * K62 + r - 1] = jj;
        }
    }
}

// ---------------- encoded distances + ratio partial ----------------
__global__ __launch_bounds__(256) void k_ratio(const double* __restrict__ Enc, const double* __restrict__ esqd,
                                               const double* __restrict__ topvd, const int* __restrict__ topi,
                                               double* __restrict__ vencd, double* __restrict__ Sp) {
    __shared__ double wp[4];
    int r = blockIdx.x * 4 + (threadIdx.x >> 6);
    int lane = threadIdx.x & 63, w = threadIdx.x >> 6;
    double ratio = 0.0;
    if (lane < K62) {
        int j = topi[(size_t)r * K62 + lane];
        const double* Er = Enc + (size_t)r * 16;
        const double* Ej = Enc + (size_t)j * 16;
        double dot = 0.0;
        #pragma unroll
        for (int q = 0; q < 16; ++q) dot = fma(Er[q], Ej[q], dot);
        double ve = sqrt(fmax(esqd[r] + esqd[j] - 2.0 * dot, 1e-12));
        vencd[(size_t)r * K62 + lane] = ve;
        ratio = topvd[(size_t)r * K62 + lane] / ve;
    }
    for (int o = 32; o > 0; o >>= 1) ratio += __shfl_down(ratio, o);
    if (lane == 0) wp[w] = ratio;
    __syncthreads();
    if (threadIdx.x == 0) Sp[blockIdx.x] = wp[0] + wp[1] + wp[2] + wp[3];
}

// ---------------- loss (merged Sp reduce; identical arithmetic order) ----------------
__global__ __launch_bounds__(256) void k_loss(const double* __restrict__ topvd, const double* __restrict__ vencd,
                                              const double* __restrict__ Sp, double* __restrict__ Lp) {
    __shared__ double wp[4];
    __shared__ double wq2[4];
    int t = threadIdx.x;
    int lane = t & 63, w = t >> 6;
    double sp = Sp[t] + Sp[t + 256] + Sp[t + 512] + Sp[t + 768];
    for (int o = 32; o > 0; o >>= 1) sp += __shfl_down(sp, o);
    if (lane == 0) wp[w] = sp;
    __syncthreads();
    double m = (wp[0] + wp[1] + wp[2] + wp[3]) * (1.0 / (4096.0 * 62.0));
    int r = blockIdx.x * 4 + w;
    double v = -1.0;
    if (lane < K62) {
        double d = topvd[(size_t)r * K62 + lane] - m * vencd[(size_t)r * K62 + lane];
        v = d * d;
    }
    for (int o = 32; o > 0; o >>= 1) { double ov = __shfl_down(v, o); v = (ov > v) ? ov : v; }
    if (lane == 0) wq2[w] = v;
    __syncthreads();
    if (t == 0) Lp[blockIdx.x] = wq2[0] + wq2[1] + wq2[2] + wq2[3];
}

__global__ __launch_bounds__(256) void k_final(const double* __restrict__ Lp, float* __restrict__ out) {
    __shared__ double wp[4];
    int t = threadIdx.x, lane = t & 63, w = t >> 6;
    double s = Lp[t] + Lp[t + 256] + Lp[t + 512] + Lp[t + 768];
    for (int o = 32; o > 0; o >>= 1) s += __shfl_down(s, o);
    if (lane == 0) wp[w] = s;
    __syncthreads();
    if (t == 0) out[0] = (float)((wp[0] + wp[1] + wp[2] + wp[3]) * (1.0 / 4096.0));
}

extern "C" void kernel_launch(void* const* d_in, const int* in_sizes, int n_in,
                              void* d_out, int out_size, void* d_ws, size_t ws_size,
                              hipStream_t stream) {
    const float* x   = (const float*)d_in[0];
    const float* cw1 = (const float*)d_in[1];
    const float* cb1 = (const float*)d_in[2];
    const float* cw2 = (const float*)d_in[3];
    const float* cb2 = (const float*)d_in[4];
    const float* cw3 = (const float*)d_in[5];
    const float* cb3 = (const float*)d_in[6];
    const float* dw  = (const float*)d_in[7];
    const float* db  = (const float*)d_in[8];

    char* wsb = (char*)d_ws;
    unsigned short* Dm16 = (unsigned short*)wsb;           // 4096*4096*2 = 33,554,432 B
    double* Enc   = (double*)(wsb + 33554432);             // 65,536 d
    double* esqd  = (double*)(wsb + 34078720);             // 4,096 d
    double* sqnd  = (double*)(wsb + 34111488);             // 4,096 d
    float*  sqnf  = (float*)(wsb + 34144256);              // 4,096 f
    double* topvd = (double*)(wsb + 34160640);             // 253,952 d
    double* vencd = (double*)(wsb + 36192256);             // 253,952 d
    int*    topi  = (int*)(wsb + 38223872);                // 253,952 i
    double* Sp    = (double*)(wsb + 39239680);             // 1,024 d
    double* Lp    = (double*)(wsb + 39247872);             // 1,024 d
    unsigned short* xb = (unsigned short*)(wsb + 39256064);// 4096*800 bf16 = 6,553,600 B
    float*  out   = (float*)d_out;

    k_prep<<<1024, 256, 0, stream>>>(x, sqnd, sqnf, xb);
    k_gram_mfma<<<528, 256, 0, stream>>>(xb, sqnf, Dm16);
    k_encoder<<<4096, 256, 0, stream>>>(x, cw1, cb1, cw2, cb2, cw3, cb3, dw, db, Enc, esqd);
    k_topsel<<<4096, 256, 0, stream>>>(Dm16, sqnd, x, topvd, topi);
    k_ratio<<<1024, 256, 0, stream>>>(Enc, esqd, topvd, topi, vencd, Sp);
    k_loss<<<1024, 256, 0, stream>>>(topvd, vencd, Sp, Lp);
    k_final<<<1, 256, 0, stream>>>(Lp, out);
}